// Round 1
// baseline (2569.391 us; speedup 1.0000x reference)
//
#include <hip/hip_runtime.h>
#include <math.h>

#define DM 1024
#define NH 16
#define DK 64
#define NB 4
#define NS 2048
#define NM (NB*NS)   // 8192 rows

// ---------------------------------------------------------------------------
// Kernel 1: QKV projection + RoPE epilogue.
// C[m][n] = sum_k A[m][k] * W[n][k]   (einsum 'bsi,oi->bso' => B^T GEMM)
// blockIdx.z selects Q/K/V. Q,K get RoPE; all written [B,H,S,DK].
// ---------------------------------------------------------------------------
__global__ __launch_bounds__(256)
void qkv_rope_kernel(const float* __restrict__ x,
                     const float* __restrict__ Wq,
                     const float* __restrict__ Wk,
                     const float* __restrict__ Wv,
                     const int*   __restrict__ pos,
                     float* __restrict__ Qo,
                     float* __restrict__ Ko,
                     float* __restrict__ Vo)
{
    const int which = blockIdx.z;
    const float* __restrict__ W   = (which == 0) ? Wq : (which == 1) ? Wk : Wv;
    float*       __restrict__ out = (which == 0) ? Qo : (which == 1) ? Ko : Vo;

    const int tid = threadIdx.x;
    const int tx = tid & 15;        // column group
    const int ty = tid >> 4;        // row group
    const int m0 = blockIdx.y * 64;
    const int n0 = blockIdx.x * 64;

    __shared__ float As[64][17];    // +1 pad: conflict-free reads
    __shared__ float Bs[64][17];

    float acc[4][4] = {};

    for (int k0 = 0; k0 < DM; k0 += 16) {
        __syncthreads();
        #pragma unroll
        for (int p = 0; p < 4; ++p) {
            int r = ty + p*16;
            As[r][tx] = x[(size_t)(m0 + r)*DM + k0 + tx];
            Bs[r][tx] = W[(size_t)(n0 + r)*DM + k0 + tx];
        }
        __syncthreads();
        #pragma unroll
        for (int kk = 0; kk < 16; ++kk) {
            float a[4], b[4];
            #pragma unroll
            for (int i = 0; i < 4; ++i) a[i] = As[ty*4 + i][kk];
            #pragma unroll
            for (int j = 0; j < 4; ++j) b[j] = Bs[tx*4 + j][kk];
            #pragma unroll
            for (int i = 0; i < 4; ++i)
                #pragma unroll
                for (int j = 0; j < 4; ++j)
                    acc[i][j] = fmaf(a[i], b[j], acc[i][j]);
        }
    }

    // Epilogue: scatter to [B,H,S,DK]; RoPE for Q/K.
    const int c0    = n0 + tx*4;        // global output channel (mult of 4)
    const int h     = c0 >> 6;
    const int dbase = c0 & 63;          // dim-in-head, even, pairs (dbase,dbase+1),(dbase+2,dbase+3)
    // ln(10000)/64
    const float LOGC = 0.14391156831212790f;

    #pragma unroll
    for (int i = 0; i < 4; ++i) {
        const int m = m0 + ty*4 + i;
        const int b = m >> 11;
        const int s = m & (NS - 1);
        float* __restrict__ orow = out + (((size_t)(b*NH + h))*NS + s)*DK;
        if (which < 2) {
            const float p = (float)pos[s];
            #pragma unroll
            for (int pp = 0; pp < 2; ++pp) {
                const int de = dbase + pp*2;
                const float freq = expf(-(float)de * LOGC);  // theta^(-de/64)
                const float ang  = p * freq;
                float sa, ca;
                sincosf(ang, &sa, &ca);
                const float xe = acc[i][pp*2];
                const float xo = acc[i][pp*2 + 1];
                orow[de]     = xe*ca - xo*sa;
                orow[de + 1] = xe*sa + xo*ca;
            }
        } else {
            #pragma unroll
            for (int j = 0; j < 4; ++j) orow[dbase + j] = acc[i][j];
        }
    }
}

// ---------------------------------------------------------------------------
// Kernel 2: causal flash attention. One block per (b*h, 64-row Q tile).
// KPs holds the K tile during QK^T, then is reused to hold P for P*V.
// Output written directly in [B,S,DM] layout for the final projection.
// ---------------------------------------------------------------------------
__global__ __launch_bounds__(256)
void attn_kernel(const float* __restrict__ Q,
                 const float* __restrict__ K,
                 const float* __restrict__ V,
                 float* __restrict__ O)
{
    const int qt  = blockIdx.x;      // 0..31
    const int bh  = blockIdx.y;      // 0..63
    const int tid = threadIdx.x;
    const int tx  = tid & 15;
    const int ty  = tid >> 4;
    const int q0  = qt * 64;

    const float* __restrict__ Qh = Q + (size_t)bh * NS * DK;
    const float* __restrict__ Kh = K + (size_t)bh * NS * DK;
    const float* __restrict__ Vh = V + (size_t)bh * NS * DK;

    __shared__ float Qs[64][65];    // padded: 4-distinct-row reads conflict-free
    __shared__ float KPs[64][65];   // K tile, reused as P tile
    __shared__ float Vs[64][64];    // unpadded: 16-addr stride-4 reads are 2-way (free)

    #pragma unroll
    for (int p = 0; p < 16; ++p) {
        int idx = p*256 + tid;
        int r = idx >> 6, c = idx & 63;
        Qs[r][c] = Qh[(size_t)(q0 + r)*DK + c];
    }

    float m_i[4], l_i[4], oacc[4][4];
    #pragma unroll
    for (int i = 0; i < 4; ++i) {
        m_i[i] = -INFINITY; l_i[i] = 0.f;
        #pragma unroll
        for (int j = 0; j < 4; ++j) oacc[i][j] = 0.f;
    }

    for (int kt = 0; kt <= qt; ++kt) {
        __syncthreads();   // previous iter's P*V / P writes done before K/V overwrite
        #pragma unroll
        for (int p = 0; p < 16; ++p) {
            int idx = p*256 + tid;
            int r = idx >> 6, c = idx & 63;
            KPs[r][c] = Kh[(size_t)(kt*64 + r)*DK + c];
            Vs[r][c]  = Vh[(size_t)(kt*64 + r)*DK + c];
        }
        __syncthreads();

        // S = Q K^T for this tile
        float sc[4][4] = {};
        #pragma unroll 8
        for (int d = 0; d < 64; ++d) {
            float a[4], b[4];
            #pragma unroll
            for (int i = 0; i < 4; ++i) a[i] = Qs[ty*4 + i][d];
            #pragma unroll
            for (int j = 0; j < 4; ++j) b[j] = KPs[tx*4 + j][d];
            #pragma unroll
            for (int i = 0; i < 4; ++i)
                #pragma unroll
                for (int j = 0; j < 4; ++j)
                    sc[i][j] = fmaf(a[i], b[j], sc[i][j]);
        }

        // scale + causal mask (only bites when kt == qt)
        const int rbase = q0 + ty*4;
        const int cbase = kt*64 + tx*4;
        #pragma unroll
        for (int i = 0; i < 4; ++i)
            #pragma unroll
            for (int j = 0; j < 4; ++j) {
                float v = sc[i][j] * 0.125f;
                sc[i][j] = (cbase + j > rbase + i) ? -INFINITY : v;
            }

        // online softmax (row groups are 16 consecutive lanes -> shfl_xor ok)
        #pragma unroll
        for (int i = 0; i < 4; ++i) {
            float mrow = fmaxf(fmaxf(sc[i][0], sc[i][1]), fmaxf(sc[i][2], sc[i][3]));
            mrow = fmaxf(mrow, __shfl_xor(mrow, 1));
            mrow = fmaxf(mrow, __shfl_xor(mrow, 2));
            mrow = fmaxf(mrow, __shfl_xor(mrow, 4));
            mrow = fmaxf(mrow, __shfl_xor(mrow, 8));
            const float mnew  = fmaxf(m_i[i], mrow);          // finite from first tile on
            const float alpha = __expf(m_i[i] - mnew);        // exp(-inf)=0 on first tile
            float rs = 0.f;
            #pragma unroll
            for (int j = 0; j < 4; ++j) { sc[i][j] = __expf(sc[i][j] - mnew); rs += sc[i][j]; }
            rs += __shfl_xor(rs, 1);
            rs += __shfl_xor(rs, 2);
            rs += __shfl_xor(rs, 4);
            rs += __shfl_xor(rs, 8);
            l_i[i] = l_i[i]*alpha + rs;
            m_i[i] = mnew;
            #pragma unroll
            for (int j = 0; j < 4; ++j) oacc[i][j] *= alpha;
        }

        __syncthreads();   // all lanes done reading K tile
        #pragma unroll
        for (int i = 0; i < 4; ++i)
            #pragma unroll
            for (int j = 0; j < 4; ++j)
                KPs[ty*4 + i][tx*4 + j] = sc[i][j];   // P overwrites K tile
        __syncthreads();

        // O += P * V
        #pragma unroll 8
        for (int d = 0; d < 64; ++d) {
            float a[4], b[4];
            #pragma unroll
            for (int i = 0; i < 4; ++i) a[i] = KPs[ty*4 + i][d];
            #pragma unroll
            for (int j = 0; j < 4; ++j) b[j] = Vs[d][tx*4 + j];
            #pragma unroll
            for (int i = 0; i < 4; ++i)
                #pragma unroll
                for (int j = 0; j < 4; ++j)
                    oacc[i][j] = fmaf(a[i], b[j], oacc[i][j]);
        }
    }

    // epilogue: divide by l, write [B,S,DM]
    const int b = bh >> 4, h = bh & 15;
    #pragma unroll
    for (int i = 0; i < 4; ++i) {
        const int sg  = q0 + ty*4 + i;
        const float inv = 1.0f / l_i[i];   // l > 0 always (diagonal unmasked)
        float* __restrict__ orow = O + ((size_t)(b*NS + sg))*DM + h*DK + tx*4;
        #pragma unroll
        for (int j = 0; j < 4; ++j) orow[j] = oacc[i][j] * inv;
    }
}

// ---------------------------------------------------------------------------
// Kernel 3: output projection, same GEMM skeleton, plain [M,N] output.
// ---------------------------------------------------------------------------
__global__ __launch_bounds__(256)
void proj_kernel(const float* __restrict__ A,
                 const float* __restrict__ W,
                 float* __restrict__ out)
{
    const int tid = threadIdx.x;
    const int tx = tid & 15;
    const int ty = tid >> 4;
    const int m0 = blockIdx.y * 64;
    const int n0 = blockIdx.x * 64;

    __shared__ float As[64][17];
    __shared__ float Bs[64][17];

    float acc[4][4] = {};

    for (int k0 = 0; k0 < DM; k0 += 16) {
        __syncthreads();
        #pragma unroll
        for (int p = 0; p < 4; ++p) {
            int r = ty + p*16;
            As[r][tx] = A[(size_t)(m0 + r)*DM + k0 + tx];
            Bs[r][tx] = W[(size_t)(n0 + r)*DM + k0 + tx];
        }
        __syncthreads();
        #pragma unroll
        for (int kk = 0; kk < 16; ++kk) {
            float a[4], b[4];
            #pragma unroll
            for (int i = 0; i < 4; ++i) a[i] = As[ty*4 + i][kk];
            #pragma unroll
            for (int j = 0; j < 4; ++j) b[j] = Bs[tx*4 + j][kk];
            #pragma unroll
            for (int i = 0; i < 4; ++i)
                #pragma unroll
                for (int j = 0; j < 4; ++j)
                    acc[i][j] = fmaf(a[i], b[j], acc[i][j]);
        }
    }

    #pragma unroll
    for (int i = 0; i < 4; ++i) {
        const int m = m0 + ty*4 + i;
        float* __restrict__ orow = out + (size_t)m*DM + n0 + tx*4;
        #pragma unroll
        for (int j = 0; j < 4; ++j) orow[j] = acc[i][j];
    }
}

// ---------------------------------------------------------------------------
extern "C" void kernel_launch(void* const* d_in, const int* in_sizes, int n_in,
                              void* d_out, int out_size, void* d_ws, size_t ws_size,
                              hipStream_t stream)
{
    const float* x   = (const float*)d_in[0];
    const float* Wq  = (const float*)d_in[1];
    const float* Wk  = (const float*)d_in[2];
    const float* Wv  = (const float*)d_in[3];
    const float* Wo  = (const float*)d_in[4];
    const int*   pos = (const int*)d_in[5];
    float* out = (float*)d_out;

    const size_t per = (size_t)NB*NH*NS*DK;   // 8388608 floats each
    float* Qb = (float*)d_ws;
    float* Kb = Qb + per;
    float* Vb = Kb + per;
    float* Ab = Vb + per;                     // attention out, [B,S,DM]

    dim3 blk(256);
    qkv_rope_kernel<<<dim3(DM/64, NM/64, 3), blk, 0, stream>>>(x, Wq, Wk, Wv, pos, Qb, Kb, Vb);
    attn_kernel    <<<dim3(NS/64, NB*NH),    blk, 0, stream>>>(Qb, Kb, Vb, Ab);
    proj_kernel    <<<dim3(DM/64, NM/64),    blk, 0, stream>>>(Ab, Wo, out);
}

// Round 2
// 1417.312 us; speedup vs baseline: 1.8129x; 1.8129x over previous
//
#include <hip/hip_runtime.h>
#include <math.h>

#define DM 1024
#define NH 16
#define DK 64
#define NB 4
#define NS 2048
#define NM (NB*NS)   // 8192 rows

typedef __attribute__((ext_vector_type(8))) __bf16 bf16x8;
typedef __attribute__((ext_vector_type(4))) float  f32x4;

// async global->LDS, 16B per lane, dest = wave-uniform base + lane*16
#define GLDS(gp, lp) __builtin_amdgcn_global_load_lds( \
    (const __attribute__((address_space(1))) void*)(gp), \
    (__attribute__((address_space(3))) void*)(lp), 16, 0, 0)

__device__ __forceinline__ unsigned short f2bf(float f) {
    unsigned int u = __float_as_uint(f);
    unsigned int r = (u + 0x7FFFu + ((u >> 16) & 1u)) >> 16;   // RNE
    return (unsigned short)r;
}

// ---------------------------------------------------------------------------
// fp32 -> bf16 convert, float4-vectorized (n4 = n/4 elements of float4)
// ---------------------------------------------------------------------------
__global__ __launch_bounds__(256)
void cvt_kernel(const float* __restrict__ src, unsigned short* __restrict__ dst, int n4)
{
    int i = blockIdx.x * 256 + threadIdx.x;
    if (i < n4) {
        float4 v = ((const float4*)src)[i];
        ushort4 o;
        o.x = f2bf(v.x); o.y = f2bf(v.y); o.z = f2bf(v.z); o.w = f2bf(v.w);
        ((ushort4*)dst)[i] = o;
    }
}

// ---------------------------------------------------------------------------
// Kernel 1: QKV projection (bf16 MFMA) + RoPE epilogue.
// C[m][n] = sum_k A[m][k] * W[n][k]  — both operands K-contiguous.
// 128x128 tile, BK=32, 4 waves, each wave 64x64 via 4x4 mfma_16x16x32_bf16.
// blockIdx.z selects Q/K/V; Q,K get RoPE; written [B,H,S,DK] fp32.
// ---------------------------------------------------------------------------
__global__ __launch_bounds__(256)
void qkv_mfma_kernel(const unsigned short* __restrict__ x16,
                     const unsigned short* __restrict__ Wq16,
                     const unsigned short* __restrict__ Wk16,
                     const unsigned short* __restrict__ Wv16,
                     const int*   __restrict__ pos,
                     float* __restrict__ Qo,
                     float* __restrict__ Ko,
                     float* __restrict__ Vo)
{
    const int which = blockIdx.z;
    const unsigned short* __restrict__ W =
        (which == 0) ? Wq16 : (which == 1) ? Wk16 : Wv16;
    float* __restrict__ out = (which == 0) ? Qo : (which == 1) ? Ko : Vo;

    __shared__ unsigned short As[128*32];   // row-major [128][32] bf16, NO pad (GLDS)
    __shared__ unsigned short Bs[128*32];

    const int tid  = threadIdx.x;
    const int wave = tid >> 6;
    const int lane = tid & 63;
    const int m0 = blockIdx.y * 128;
    const int n0 = blockIdx.x * 128;
    const int wm = (wave >> 1) * 64;
    const int wn = (wave & 1) * 64;

    // staging map: wave stages rows [wave*32, wave*32+32) of A and of B,
    // two GLDS each (16 rows x 64B = 1KiB per instruction)
    const int srow   = wave*32 + (lane >> 2);
    const int schunk = (lane & 3) * 8;                  // bf16 elements
    const unsigned short* ga0 = x16 + (size_t)(m0 + srow     )*DM + schunk;
    const unsigned short* ga1 = x16 + (size_t)(m0 + srow + 16)*DM + schunk;
    const unsigned short* gb0 = W   + (size_t)(n0 + srow     )*DM + schunk;
    const unsigned short* gb1 = W   + (size_t)(n0 + srow + 16)*DM + schunk;
    unsigned short* la0 = &As[(wave*32     )*32];
    unsigned short* la1 = &As[(wave*32 + 16)*32];
    unsigned short* lb0 = &Bs[(wave*32     )*32];
    unsigned short* lb1 = &Bs[(wave*32 + 16)*32];

    const int fr = lane & 15;          // row within 16-tile (A and B frags)
    const int q8 = (lane >> 4) * 8;    // k-offset within BK=32

    f32x4 acc[4][4];
    #pragma unroll
    for (int i = 0; i < 4; ++i)
        #pragma unroll
        for (int j = 0; j < 4; ++j)
            acc[i][j] = (f32x4){0.f, 0.f, 0.f, 0.f};

    for (int k0 = 0; k0 < DM; k0 += 32) {
        __syncthreads();                 // LDS free to overwrite
        GLDS(ga0 + k0, la0);
        GLDS(ga1 + k0, la1);
        GLDS(gb0 + k0, lb0);
        GLDS(gb1 + k0, lb1);
        __syncthreads();                 // staging complete (vmcnt drained)

        bf16x8 af[4], bf[4];
        #pragma unroll
        for (int i = 0; i < 4; ++i)
            af[i] = *(const bf16x8*)&As[(wm + i*16 + fr)*32 + q8];
        #pragma unroll
        for (int j = 0; j < 4; ++j)
            bf[j] = *(const bf16x8*)&Bs[(wn + j*16 + fr)*32 + q8];
        #pragma unroll
        for (int i = 0; i < 4; ++i)
            #pragma unroll
            for (int j = 0; j < 4; ++j)
                acc[i][j] = __builtin_amdgcn_mfma_f32_16x16x32_bf16(
                                af[i], bf[j], acc[i][j], 0, 0, 0);
    }

    // Epilogue: C/D layout col=lane&15, row=quad*4+reg. RoPE via lane^1 pair.
    const float LOGC = 0.14391156831212790f;  // ln(10000)/64
    const int col  = lane & 15;
    const int quad = lane >> 4;
    #pragma unroll
    for (int j = 0; j < 4; ++j) {
        const int n = n0 + wn + j*16 + col;
        const int h = n >> 6;
        const int d = n & 63;
        const int odd = d & 1;
        float freq = 0.f;
        if (which < 2) freq = expf(-(float)(d & ~1) * LOGC);
        #pragma unroll
        for (int i = 0; i < 4; ++i) {
            #pragma unroll
            for (int r = 0; r < 4; ++r) {
                const int m = m0 + wm + i*16 + quad*4 + r;
                const int b = m >> 11;
                const int s = m & (NS - 1);
                float v = acc[i][j][r];
                if (which < 2) {
                    const float pv = __shfl_xor(v, 1);   // partner of the (even,odd) pair
                    float sa, ca;
                    sincosf((float)pos[s] * freq, &sa, &ca);
                    v = odd ? (pv*sa + v*ca) : (v*ca - pv*sa);
                }
                out[(((size_t)(b*NH + h))*NS + s)*DK + d] = v;
            }
        }
    }
}

// ---------------------------------------------------------------------------
// Kernel 2: causal flash attention (fp32, unchanged from R1).
// ---------------------------------------------------------------------------
__global__ __launch_bounds__(256)
void attn_kernel(const float* __restrict__ Q,
                 const float* __restrict__ K,
                 const float* __restrict__ V,
                 float* __restrict__ O)
{
    const int qt  = blockIdx.x;      // 0..31
    const int bh  = blockIdx.y;      // 0..63
    const int tid = threadIdx.x;
    const int tx  = tid & 15;
    const int ty  = tid >> 4;
    const int q0  = qt * 64;

    const float* __restrict__ Qh = Q + (size_t)bh * NS * DK;
    const float* __restrict__ Kh = K + (size_t)bh * NS * DK;
    const float* __restrict__ Vh = V + (size_t)bh * NS * DK;

    __shared__ float Qs[64][65];
    __shared__ float KPs[64][65];
    __shared__ float Vs[64][64];

    #pragma unroll
    for (int p = 0; p < 16; ++p) {
        int idx = p*256 + tid;
        int r = idx >> 6, c = idx & 63;
        Qs[r][c] = Qh[(size_t)(q0 + r)*DK + c];
    }

    float m_i[4], l_i[4], oacc[4][4];
    #pragma unroll
    for (int i = 0; i < 4; ++i) {
        m_i[i] = -INFINITY; l_i[i] = 0.f;
        #pragma unroll
        for (int j = 0; j < 4; ++j) oacc[i][j] = 0.f;
    }

    for (int kt = 0; kt <= qt; ++kt) {
        __syncthreads();
        #pragma unroll
        for (int p = 0; p < 16; ++p) {
            int idx = p*256 + tid;
            int r = idx >> 6, c = idx & 63;
            KPs[r][c] = Kh[(size_t)(kt*64 + r)*DK + c];
            Vs[r][c]  = Vh[(size_t)(kt*64 + r)*DK + c];
        }
        __syncthreads();

        float sc[4][4] = {};
        #pragma unroll 8
        for (int d = 0; d < 64; ++d) {
            float a[4], b[4];
            #pragma unroll
            for (int i = 0; i < 4; ++i) a[i] = Qs[ty*4 + i][d];
            #pragma unroll
            for (int j = 0; j < 4; ++j) b[j] = KPs[tx*4 + j][d];
            #pragma unroll
            for (int i = 0; i < 4; ++i)
                #pragma unroll
                for (int j = 0; j < 4; ++j)
                    sc[i][j] = fmaf(a[i], b[j], sc[i][j]);
        }

        const int rbase = q0 + ty*4;
        const int cbase = kt*64 + tx*4;
        #pragma unroll
        for (int i = 0; i < 4; ++i)
            #pragma unroll
            for (int j = 0; j < 4; ++j) {
                float v = sc[i][j] * 0.125f;
                sc[i][j] = (cbase + j > rbase + i) ? -INFINITY : v;
            }

        #pragma unroll
        for (int i = 0; i < 4; ++i) {
            float mrow = fmaxf(fmaxf(sc[i][0], sc[i][1]), fmaxf(sc[i][2], sc[i][3]));
            mrow = fmaxf(mrow, __shfl_xor(mrow, 1));
            mrow = fmaxf(mrow, __shfl_xor(mrow, 2));
            mrow = fmaxf(mrow, __shfl_xor(mrow, 4));
            mrow = fmaxf(mrow, __shfl_xor(mrow, 8));
            const float mnew  = fmaxf(m_i[i], mrow);
            const float alpha = __expf(m_i[i] - mnew);
            float rs = 0.f;
            #pragma unroll
            for (int j = 0; j < 4; ++j) { sc[i][j] = __expf(sc[i][j] - mnew); rs += sc[i][j]; }
            rs += __shfl_xor(rs, 1);
            rs += __shfl_xor(rs, 2);
            rs += __shfl_xor(rs, 4);
            rs += __shfl_xor(rs, 8);
            l_i[i] = l_i[i]*alpha + rs;
            m_i[i] = mnew;
            #pragma unroll
            for (int j = 0; j < 4; ++j) oacc[i][j] *= alpha;
        }

        __syncthreads();
        #pragma unroll
        for (int i = 0; i < 4; ++i)
            #pragma unroll
            for (int j = 0; j < 4; ++j)
                KPs[ty*4 + i][tx*4 + j] = sc[i][j];
        __syncthreads();

        #pragma unroll 8
        for (int d = 0; d < 64; ++d) {
            float a[4], b[4];
            #pragma unroll
            for (int i = 0; i < 4; ++i) a[i] = KPs[ty*4 + i][d];
            #pragma unroll
            for (int j = 0; j < 4; ++j) b[j] = Vs[d][tx*4 + j];
            #pragma unroll
            for (int i = 0; i < 4; ++i)
                #pragma unroll
                for (int j = 0; j < 4; ++j)
                    oacc[i][j] = fmaf(a[i], b[j], oacc[i][j]);
        }
    }

    const int b = bh >> 4, h = bh & 15;
    #pragma unroll
    for (int i = 0; i < 4; ++i) {
        const int sg  = q0 + ty*4 + i;
        const float inv = 1.0f / l_i[i];
        float* __restrict__ orow = O + ((size_t)(b*NS + sg))*DM + h*DK + tx*4;
        #pragma unroll
        for (int j = 0; j < 4; ++j) orow[j] = oacc[i][j] * inv;
    }
}

// ---------------------------------------------------------------------------
// Kernel 3: output projection (bf16 MFMA), plain [M,N] fp32 output.
// ---------------------------------------------------------------------------
__global__ __launch_bounds__(256)
void proj_mfma_kernel(const unsigned short* __restrict__ A16,
                      const unsigned short* __restrict__ W16,
                      float* __restrict__ out)
{
    __shared__ unsigned short As[128*32];
    __shared__ unsigned short Bs[128*32];

    const int tid  = threadIdx.x;
    const int wave = tid >> 6;
    const int lane = tid & 63;
    const int m0 = blockIdx.y * 128;
    const int n0 = blockIdx.x * 128;
    const int wm = (wave >> 1) * 64;
    const int wn = (wave & 1) * 64;

    const int srow   = wave*32 + (lane >> 2);
    const int schunk = (lane & 3) * 8;
    const unsigned short* ga0 = A16 + (size_t)(m0 + srow     )*DM + schunk;
    const unsigned short* ga1 = A16 + (size_t)(m0 + srow + 16)*DM + schunk;
    const unsigned short* gb0 = W16 + (size_t)(n0 + srow     )*DM + schunk;
    const unsigned short* gb1 = W16 + (size_t)(n0 + srow + 16)*DM + schunk;
    unsigned short* la0 = &As[(wave*32     )*32];
    unsigned short* la1 = &As[(wave*32 + 16)*32];
    unsigned short* lb0 = &Bs[(wave*32     )*32];
    unsigned short* lb1 = &Bs[(wave*32 + 16)*32];

    const int fr = lane & 15;
    const int q8 = (lane >> 4) * 8;

    f32x4 acc[4][4];
    #pragma unroll
    for (int i = 0; i < 4; ++i)
        #pragma unroll
        for (int j = 0; j < 4; ++j)
            acc[i][j] = (f32x4){0.f, 0.f, 0.f, 0.f};

    for (int k0 = 0; k0 < DM; k0 += 32) {
        __syncthreads();
        GLDS(ga0 + k0, la0);
        GLDS(ga1 + k0, la1);
        GLDS(gb0 + k0, lb0);
        GLDS(gb1 + k0, lb1);
        __syncthreads();

        bf16x8 af[4], bf[4];
        #pragma unroll
        for (int i = 0; i < 4; ++i)
            af[i] = *(const bf16x8*)&As[(wm + i*16 + fr)*32 + q8];
        #pragma unroll
        for (int j = 0; j < 4; ++j)
            bf[j] = *(const bf16x8*)&Bs[(wn + j*16 + fr)*32 + q8];
        #pragma unroll
        for (int i = 0; i < 4; ++i)
            #pragma unroll
            for (int j = 0; j < 4; ++j)
                acc[i][j] = __builtin_amdgcn_mfma_f32_16x16x32_bf16(
                                af[i], bf[j], acc[i][j], 0, 0, 0);
    }

    const int col  = lane & 15;
    const int quad = lane >> 4;
    #pragma unroll
    for (int j = 0; j < 4; ++j) {
        const int n = n0 + wn + j*16 + col;
        #pragma unroll
        for (int i = 0; i < 4; ++i) {
            #pragma unroll
            for (int r = 0; r < 4; ++r) {
                const int m = m0 + wm + i*16 + quad*4 + r;
                out[(size_t)m*DM + n] = acc[i][j][r];
            }
        }
    }
}

// ---------------------------------------------------------------------------
extern "C" void kernel_launch(void* const* d_in, const int* in_sizes, int n_in,
                              void* d_out, int out_size, void* d_ws, size_t ws_size,
                              hipStream_t stream)
{
    const float* x   = (const float*)d_in[0];
    const float* Wq  = (const float*)d_in[1];
    const float* Wk  = (const float*)d_in[2];
    const float* Wv  = (const float*)d_in[3];
    const float* Wo  = (const float*)d_in[4];
    const int*   pos = (const int*)d_in[5];
    float* out = (float*)d_out;

    const size_t per = (size_t)NB*NH*NS*DK;   // 8388608
    float* Qb = (float*)d_ws;
    float* Kb = Qb + per;
    float* Vb = Kb + per;
    float* Ab = Vb + per;                     // attention out, [B,S,DM] fp32
    unsigned short* x16  = (unsigned short*)(Ab + per);
    unsigned short* Wq16 = x16 + per;
    unsigned short* Wk16 = Wq16 + (size_t)DM*DM;
    unsigned short* Wv16 = Wk16 + (size_t)DM*DM;
    unsigned short* Wo16 = Wv16 + (size_t)DM*DM;
    unsigned short* Ab16 = x16;               // alias: x16 dead after qkv_mfma

    dim3 blk(256);
    cvt_kernel<<<dim3((int)(per/4/256)), blk, 0, stream>>>(x, x16, (int)(per/4));
    cvt_kernel<<<dim3(DM*DM/4/256), blk, 0, stream>>>(Wq, Wq16, DM*DM/4);
    cvt_kernel<<<dim3(DM*DM/4/256), blk, 0, stream>>>(Wk, Wk16, DM*DM/4);
    cvt_kernel<<<dim3(DM*DM/4/256), blk, 0, stream>>>(Wv, Wv16, DM*DM/4);
    cvt_kernel<<<dim3(DM*DM/4/256), blk, 0, stream>>>(Wo, Wo16, DM*DM/4);

    qkv_mfma_kernel<<<dim3(DM/128, NM/128, 3), blk, 0, stream>>>(
        x16, Wq16, Wk16, Wv16, pos, Qb, Kb, Vb);
    attn_kernel<<<dim3(NS/64, NB*NH), blk, 0, stream>>>(Qb, Kb, Vb, Ab);
    cvt_kernel<<<dim3((int)(per/4/256)), blk, 0, stream>>>(Ab, Ab16, (int)(per/4));
    proj_mfma_kernel<<<dim3(DM/128, NM/128), blk, 0, stream>>>(Ab16, Wo16, out);
}

// Round 3
// 962.892 us; speedup vs baseline: 2.6684x; 1.4719x over previous
//
#include <hip/hip_runtime.h>
#include <math.h>

#define DM 1024
#define NH 16
#define DK 64
#define NB 4
#define NS 2048
#define NM (NB*NS)   // 8192 rows

typedef __attribute__((ext_vector_type(8))) __bf16 bf16x8;
typedef __attribute__((ext_vector_type(4))) float  f32x4;

// async global->LDS, 16B per lane, dest = wave-uniform base + lane*16
#define GLDS(gp, lp) __builtin_amdgcn_global_load_lds( \
    (const __attribute__((address_space(1))) void*)(gp), \
    (__attribute__((address_space(3))) void*)(lp), 16, 0, 0)

__device__ __forceinline__ unsigned short f2bf(float f) {
    unsigned int u = __float_as_uint(f);
    unsigned int r = (u + 0x7FFFu + ((u >> 16) & 1u)) >> 16;   // RNE
    return (unsigned short)r;
}

// ---------------------------------------------------------------------------
// fp32 -> bf16 convert
// ---------------------------------------------------------------------------
__global__ __launch_bounds__(256)
void cvt_kernel(const float* __restrict__ src, unsigned short* __restrict__ dst, int n4)
{
    int i = blockIdx.x * 256 + threadIdx.x;
    if (i < n4) {
        float4 v = ((const float4*)src)[i];
        ushort4 o;
        o.x = f2bf(v.x); o.y = f2bf(v.y); o.z = f2bf(v.z); o.w = f2bf(v.w);
        ((ushort4*)dst)[i] = o;
    }
}

// ---------------------------------------------------------------------------
// Kernel 1: QKV projection (bf16 MFMA) + RoPE epilogue, bf16 outputs.
// Q,K -> [bh][s][d] bf16 (with RoPE); V -> [bh][d][s] bf16 (pre-transposed).
// ---------------------------------------------------------------------------
__global__ __launch_bounds__(256)
void qkv_mfma_kernel(const unsigned short* __restrict__ x16,
                     const unsigned short* __restrict__ Wq16,
                     const unsigned short* __restrict__ Wk16,
                     const unsigned short* __restrict__ Wv16,
                     const int*   __restrict__ pos,
                     unsigned short* __restrict__ Qo,
                     unsigned short* __restrict__ Ko,
                     unsigned short* __restrict__ Vt)
{
    const int which = blockIdx.z;
    const unsigned short* __restrict__ W =
        (which == 0) ? Wq16 : (which == 1) ? Wk16 : Wv16;

    __shared__ unsigned short As[128*32];
    __shared__ unsigned short Bs[128*32];

    const int tid  = threadIdx.x;
    const int wave = tid >> 6;
    const int lane = tid & 63;
    const int m0 = blockIdx.y * 128;
    const int n0 = blockIdx.x * 128;
    const int wm = (wave >> 1) * 64;
    const int wn = (wave & 1) * 64;

    const int srow   = wave*32 + (lane >> 2);
    const int schunk = (lane & 3) * 8;
    const unsigned short* ga0 = x16 + (size_t)(m0 + srow     )*DM + schunk;
    const unsigned short* ga1 = x16 + (size_t)(m0 + srow + 16)*DM + schunk;
    const unsigned short* gb0 = W   + (size_t)(n0 + srow     )*DM + schunk;
    const unsigned short* gb1 = W   + (size_t)(n0 + srow + 16)*DM + schunk;
    unsigned short* la0 = &As[(wave*32     )*32];
    unsigned short* la1 = &As[(wave*32 + 16)*32];
    unsigned short* lb0 = &Bs[(wave*32     )*32];
    unsigned short* lb1 = &Bs[(wave*32 + 16)*32];

    const int fr = lane & 15;
    const int q8 = (lane >> 4) * 8;

    f32x4 acc[4][4];
    #pragma unroll
    for (int i = 0; i < 4; ++i)
        #pragma unroll
        for (int j = 0; j < 4; ++j)
            acc[i][j] = (f32x4){0.f, 0.f, 0.f, 0.f};

    for (int k0 = 0; k0 < DM; k0 += 32) {
        __syncthreads();
        GLDS(ga0 + k0, la0);
        GLDS(ga1 + k0, la1);
        GLDS(gb0 + k0, lb0);
        GLDS(gb1 + k0, lb1);
        __syncthreads();

        bf16x8 af[4], bf[4];
        #pragma unroll
        for (int i = 0; i < 4; ++i)
            af[i] = *(const bf16x8*)&As[(wm + i*16 + fr)*32 + q8];
        #pragma unroll
        for (int j = 0; j < 4; ++j)
            bf[j] = *(const bf16x8*)&Bs[(wn + j*16 + fr)*32 + q8];
        #pragma unroll
        for (int i = 0; i < 4; ++i)
            #pragma unroll
            for (int j = 0; j < 4; ++j)
                acc[i][j] = __builtin_amdgcn_mfma_f32_16x16x32_bf16(
                                af[i], bf[j], acc[i][j], 0, 0, 0);
    }

    // Epilogue: C/D layout col=lane&15, row=quad*4+reg.
    const float LOGC = 0.14391156831212790f;  // ln(10000)/64
    const int col  = lane & 15;
    const int quad = lane >> 4;
    #pragma unroll
    for (int j = 0; j < 4; ++j) {
        const int n = n0 + wn + j*16 + col;
        const int h = n >> 6;
        const int d = n & 63;
        const int odd = d & 1;
        float freq = 0.f;
        if (which < 2) freq = expf(-(float)(d & ~1) * LOGC);
        #pragma unroll
        for (int i = 0; i < 4; ++i) {
            const int mb = m0 + wm + i*16 + quad*4;   // 4 consecutive m
            const int b  = mb >> 11;
            const int sb = mb & (NS - 1);
            if (which < 2) {
                unsigned short* __restrict__ out = (which == 0) ? Qo : Ko;
                #pragma unroll
                for (int r = 0; r < 4; ++r) {
                    const int s = sb + r;
                    float v = acc[i][j][r];
                    const float pv = __shfl_xor(v, 1);
                    float sa, ca;
                    sincosf((float)pos[s] * freq, &sa, &ca);
                    v = odd ? (pv*sa + v*ca) : (v*ca - pv*sa);
                    out[(((size_t)(b*NH + h))*NS + s)*DK + d] = f2bf(v);
                }
            } else {
                ushort4 o;
                o.x = f2bf(acc[i][j][0]); o.y = f2bf(acc[i][j][1]);
                o.z = f2bf(acc[i][j][2]); o.w = f2bf(acc[i][j][3]);
                *(ushort4*)&Vt[(((size_t)(b*NH + h))*DK + d)*NS + sb] = o;
            }
        }
    }
}

// ---------------------------------------------------------------------------
// Kernel 2: causal flash attention, bf16 MFMA.
// Block: 128 Q-rows, 4 waves x 32 rows. K-tiles of 64. V arrives transposed.
// Output: bf16 [B][S][DM] (feeds proj directly).
// ---------------------------------------------------------------------------
__global__ __launch_bounds__(256)
void attn_mfma_kernel(const unsigned short* __restrict__ Q,
                      const unsigned short* __restrict__ K,
                      const unsigned short* __restrict__ Vt,
                      unsigned short* __restrict__ O)
{
    const int qt   = blockIdx.x;      // 0..15
    const int bh   = blockIdx.y;      // 0..63
    const int tid  = threadIdx.x;
    const int wave = tid >> 6;
    const int lane = tid & 63;
    const int q0   = qt * 128;
    const int wq0  = wave * 32;

    const int fr   = lane & 15;
    const int q8   = (lane >> 4) * 8;
    const int col  = lane & 15;
    const int quad = lane >> 4;

    const unsigned short* __restrict__ Qh = Q  + (size_t)bh * NS * DK;
    const unsigned short* __restrict__ Kh = K  + (size_t)bh * NS * DK;
    const unsigned short* __restrict__ Vh = Vt + (size_t)bh * DK * NS;

    __shared__ unsigned short Qs[128*64];       // [qrow][d]
    __shared__ unsigned short Ks[64*64];        // [krow][d]
    __shared__ unsigned short Vs[64*64];        // [d][k]  (V^T tile)
    __shared__ unsigned short Ps[4*32*72];      // per-wave P [q][k], stride 72

    // stage this wave's own 32 Q rows (4 GLDS)
    {
        const int r  = lane >> 3;
        const int c8 = (lane & 7) * 8;
        #pragma unroll
        for (int p = 0; p < 4; ++p) {
            const int row = wq0 + p*8;
            GLDS(Qh + (size_t)(q0 + row + r)*DK + c8, &Qs[row*64]);
        }
    }

    float m_i[2][4], l_i[2][4];
    f32x4 oacc[2][4];
    #pragma unroll
    for (int i = 0; i < 2; ++i)
        #pragma unroll
        for (int r = 0; r < 4; ++r) { m_i[i][r] = -INFINITY; l_i[i][r] = 0.f; }
    #pragma unroll
    for (int i = 0; i < 2; ++i)
        #pragma unroll
        for (int j = 0; j < 4; ++j)
            oacc[i][j] = (f32x4){0.f, 0.f, 0.f, 0.f};

    const int ktmax = (q0 + 127) >> 6;   // 2*qt+1

    for (int kt = 0; kt <= ktmax; ++kt) {
        __syncthreads();   // prior reads of Ks/Vs done
        {
            const int r  = lane >> 3;
            const int c8 = (lane & 7) * 8;
            #pragma unroll
            for (int p = 0; p < 2; ++p) {
                const int row = wave*16 + p*8;
                GLDS(Kh + (size_t)(kt*64 + row + r)*DK + c8, &Ks[row*64]);
                GLDS(Vh + (size_t)(row + r)*NS + kt*64 + c8, &Vs[row*64]);
            }
        }
        __syncthreads();   // staging drained (vmcnt 0) — Q covered on first iter

        const bool active = (kt*64) <= (q0 + wq0 + 31);
        if (active) {
            // ---- S = Q K^T (wave: 32x64) ----
            f32x4 sacc[2][4];
            #pragma unroll
            for (int i = 0; i < 2; ++i)
                #pragma unroll
                for (int j = 0; j < 4; ++j)
                    sacc[i][j] = (f32x4){0.f, 0.f, 0.f, 0.f};
            #pragma unroll
            for (int kk = 0; kk < 2; ++kk) {
                bf16x8 aq[2], bk[4];
                #pragma unroll
                for (int i = 0; i < 2; ++i)
                    aq[i] = *(const bf16x8*)&Qs[(wq0 + i*16 + fr)*64 + kk*32 + q8];
                #pragma unroll
                for (int j = 0; j < 4; ++j)
                    bk[j] = *(const bf16x8*)&Ks[(j*16 + fr)*64 + kk*32 + q8];
                #pragma unroll
                for (int i = 0; i < 2; ++i)
                    #pragma unroll
                    for (int j = 0; j < 4; ++j)
                        sacc[i][j] = __builtin_amdgcn_mfma_f32_16x16x32_bf16(
                                        aq[i], bk[j], sacc[i][j], 0, 0, 0);
            }

            // ---- scale + causal mask ----
            const bool needmask = (kt*64 + 63) > (q0 + wq0);
            #pragma unroll
            for (int i = 0; i < 2; ++i)
                #pragma unroll
                for (int j = 0; j < 4; ++j)
                    #pragma unroll
                    for (int r = 0; r < 4; ++r) {
                        float v = sacc[i][j][r] * 0.125f;
                        if (needmask) {
                            const int sg = q0 + wq0 + i*16 + quad*4 + r;
                            const int kg = kt*64 + j*16 + col;
                            if (kg > sg) v = -INFINITY;
                        }
                        sacc[i][j][r] = v;
                    }

            // ---- online softmax; P left in sacc ----
            #pragma unroll
            for (int i = 0; i < 2; ++i)
                #pragma unroll
                for (int r = 0; r < 4; ++r) {
                    float mx = fmaxf(fmaxf(sacc[i][0][r], sacc[i][1][r]),
                                     fmaxf(sacc[i][2][r], sacc[i][3][r]));
                    mx = fmaxf(mx, __shfl_xor(mx, 1));
                    mx = fmaxf(mx, __shfl_xor(mx, 2));
                    mx = fmaxf(mx, __shfl_xor(mx, 4));
                    mx = fmaxf(mx, __shfl_xor(mx, 8));
                    const float mnew  = fmaxf(m_i[i][r], mx);
                    const float alpha = __expf(m_i[i][r] - mnew);
                    float rs = 0.f;
                    #pragma unroll
                    for (int j = 0; j < 4; ++j) {
                        const float p = __expf(sacc[i][j][r] - mnew);
                        sacc[i][j][r] = p;
                        rs += p;
                    }
                    rs += __shfl_xor(rs, 1);
                    rs += __shfl_xor(rs, 2);
                    rs += __shfl_xor(rs, 4);
                    rs += __shfl_xor(rs, 8);
                    l_i[i][r] = l_i[i][r]*alpha + rs;
                    m_i[i][r] = mnew;
                    #pragma unroll
                    for (int j = 0; j < 4; ++j) oacc[i][j][r] *= alpha;
                }

            // ---- P: C-layout -> LDS [q][k] (per-wave region) ----
            unsigned short* Pw = &Ps[wave*32*72];
            #pragma unroll
            for (int i = 0; i < 2; ++i)
                #pragma unroll
                for (int j = 0; j < 4; ++j)
                    #pragma unroll
                    for (int r = 0; r < 4; ++r)
                        Pw[(i*16 + quad*4 + r)*72 + j*16 + col] = f2bf(sacc[i][j][r]);
            asm volatile("s_waitcnt lgkmcnt(0)" ::: "memory");

            // ---- O += P V ----
            #pragma unroll
            for (int kk = 0; kk < 2; ++kk) {
                bf16x8 ap[2], bv[4];
                #pragma unroll
                for (int i = 0; i < 2; ++i)
                    ap[i] = *(const bf16x8*)&Pw[(i*16 + fr)*72 + kk*32 + q8];
                #pragma unroll
                for (int j = 0; j < 4; ++j)
                    bv[j] = *(const bf16x8*)&Vs[(j*16 + fr)*64 + kk*32 + q8];
                #pragma unroll
                for (int i = 0; i < 2; ++i)
                    #pragma unroll
                    for (int j = 0; j < 4; ++j)
                        oacc[i][j] = __builtin_amdgcn_mfma_f32_16x16x32_bf16(
                                        ap[i], bv[j], oacc[i][j], 0, 0, 0);
            }
        }
    }

    // ---- epilogue: O / l, write bf16 [B][S][DM] ----
    const int b = bh >> 4, h = bh & 15;
    #pragma unroll
    for (int i = 0; i < 2; ++i)
        #pragma unroll
        for (int r = 0; r < 4; ++r) {
            const float inv = 1.0f / l_i[i][r];
            const int sg = q0 + wq0 + i*16 + quad*4 + r;
            #pragma unroll
            for (int j = 0; j < 4; ++j) {
                const int d = j*16 + col;
                O[((size_t)(b*NS + sg))*DM + h*64 + d] = f2bf(oacc[i][j][r] * inv);
            }
        }
}

// ---------------------------------------------------------------------------
// Kernel 3: output projection (bf16 MFMA), fp32 output.
// ---------------------------------------------------------------------------
__global__ __launch_bounds__(256)
void proj_mfma_kernel(const unsigned short* __restrict__ A16,
                      const unsigned short* __restrict__ W16,
                      float* __restrict__ out)
{
    __shared__ unsigned short As[128*32];
    __shared__ unsigned short Bs[128*32];

    const int tid  = threadIdx.x;
    const int wave = tid >> 6;
    const int lane = tid & 63;
    const int m0 = blockIdx.y * 128;
    const int n0 = blockIdx.x * 128;
    const int wm = (wave >> 1) * 64;
    const int wn = (wave & 1) * 64;

    const int srow   = wave*32 + (lane >> 2);
    const int schunk = (lane & 3) * 8;
    const unsigned short* ga0 = A16 + (size_t)(m0 + srow     )*DM + schunk;
    const unsigned short* ga1 = A16 + (size_t)(m0 + srow + 16)*DM + schunk;
    const unsigned short* gb0 = W16 + (size_t)(n0 + srow     )*DM + schunk;
    const unsigned short* gb1 = W16 + (size_t)(n0 + srow + 16)*DM + schunk;
    unsigned short* la0 = &As[(wave*32     )*32];
    unsigned short* la1 = &As[(wave*32 + 16)*32];
    unsigned short* lb0 = &Bs[(wave*32     )*32];
    unsigned short* lb1 = &Bs[(wave*32 + 16)*32];

    const int fr = lane & 15;
    const int q8 = (lane >> 4) * 8;

    f32x4 acc[4][4];
    #pragma unroll
    for (int i = 0; i < 4; ++i)
        #pragma unroll
        for (int j = 0; j < 4; ++j)
            acc[i][j] = (f32x4){0.f, 0.f, 0.f, 0.f};

    for (int k0 = 0; k0 < DM; k0 += 32) {
        __syncthreads();
        GLDS(ga0 + k0, la0);
        GLDS(ga1 + k0, la1);
        GLDS(gb0 + k0, lb0);
        GLDS(gb1 + k0, lb1);
        __syncthreads();

        bf16x8 af[4], bf[4];
        #pragma unroll
        for (int i = 0; i < 4; ++i)
            af[i] = *(const bf16x8*)&As[(wm + i*16 + fr)*32 + q8];
        #pragma unroll
        for (int j = 0; j < 4; ++j)
            bf[j] = *(const bf16x8*)&Bs[(wn + j*16 + fr)*32 + q8];
        #pragma unroll
        for (int i = 0; i < 4; ++i)
            #pragma unroll
            for (int j = 0; j < 4; ++j)
                acc[i][j] = __builtin_amdgcn_mfma_f32_16x16x32_bf16(
                                af[i], bf[j], acc[i][j], 0, 0, 0);
    }

    const int col  = lane & 15;
    const int quad = lane >> 4;
    #pragma unroll
    for (int j = 0; j < 4; ++j) {
        const int n = n0 + wn + j*16 + col;
        #pragma unroll
        for (int i = 0; i < 4; ++i) {
            #pragma unroll
            for (int r = 0; r < 4; ++r) {
                const int m = m0 + wm + i*16 + quad*4 + r;
                out[(size_t)m*DM + n] = acc[i][j][r];
            }
        }
    }
}

// ---------------------------------------------------------------------------
extern "C" void kernel_launch(void* const* d_in, const int* in_sizes, int n_in,
                              void* d_out, int out_size, void* d_ws, size_t ws_size,
                              hipStream_t stream)
{
    const float* x   = (const float*)d_in[0];
    const float* Wq  = (const float*)d_in[1];
    const float* Wk  = (const float*)d_in[2];
    const float* Wv  = (const float*)d_in[3];
    const float* Wo  = (const float*)d_in[4];
    const int*   pos = (const int*)d_in[5];
    float* out = (float*)d_out;

    const size_t per = (size_t)NB*NH*NS*DK;   // 8388608 elements
    unsigned short* x16  = (unsigned short*)d_ws;
    unsigned short* Wq16 = x16  + per;
    unsigned short* Wk16 = Wq16 + (size_t)DM*DM;
    unsigned short* Wv16 = Wk16 + (size_t)DM*DM;
    unsigned short* Wo16 = Wv16 + (size_t)DM*DM;
    unsigned short* Q16  = Wo16 + (size_t)DM*DM;
    unsigned short* K16  = Q16  + per;
    unsigned short* Vt16 = K16  + per;
    unsigned short* Ab16 = Vt16 + per;        // attention out, bf16 [B][S][DM]

    dim3 blk(256);
    cvt_kernel<<<dim3((int)(per/4/256)), blk, 0, stream>>>(x, x16, (int)(per/4));
    cvt_kernel<<<dim3(DM*DM/4/256), blk, 0, stream>>>(Wq, Wq16, DM*DM/4);
    cvt_kernel<<<dim3(DM*DM/4/256), blk, 0, stream>>>(Wk, Wk16, DM*DM/4);
    cvt_kernel<<<dim3(DM*DM/4/256), blk, 0, stream>>>(Wv, Wv16, DM*DM/4);
    cvt_kernel<<<dim3(DM*DM/4/256), blk, 0, stream>>>(Wo, Wo16, DM*DM/4);

    qkv_mfma_kernel<<<dim3(DM/128, NM/128, 3), blk, 0, stream>>>(
        x16, Wq16, Wk16, Wv16, pos, Q16, K16, Vt16);
    attn_mfma_kernel<<<dim3(NS/128, NB*NH), blk, 0, stream>>>(Q16, K16, Vt16, Ab16);
    proj_mfma_kernel<<<dim3(DM/128, NM/128), blk, 0, stream>>>(Ab16, Wo16, out);
}

// Round 4
// 938.183 us; speedup vs baseline: 2.7387x; 1.0263x over previous
//
#include <hip/hip_runtime.h>
#include <math.h>

#define DM 1024
#define NH 16
#define DK 64
#define NB 4
#define NS 2048
#define NM (NB*NS)   // 8192 rows

typedef __attribute__((ext_vector_type(8))) __bf16 bf16x8;
typedef __attribute__((ext_vector_type(4))) float  f32x4;

// async global->LDS, 16B per lane, dest = wave-uniform base + lane*16
#define GLDS(gp, lp) __builtin_amdgcn_global_load_lds( \
    (const __attribute__((address_space(1))) void*)(gp), \
    (__attribute__((address_space(3))) void*)(lp), 16, 0, 0)

__device__ __forceinline__ unsigned short f2bf(float f) {
    unsigned int u = __float_as_uint(f);
    unsigned int r = (u + 0x7FFFu + ((u >> 16) & 1u)) >> 16;   // RNE
    return (unsigned short)r;
}

// ---------------------------------------------------------------------------
// fp32 -> bf16 convert
// ---------------------------------------------------------------------------
__global__ __launch_bounds__(256)
void cvt_kernel(const float* __restrict__ src, unsigned short* __restrict__ dst, int n4)
{
    int i = blockIdx.x * 256 + threadIdx.x;
    if (i < n4) {
        float4 v = ((const float4*)src)[i];
        ushort4 o;
        o.x = f2bf(v.x); o.y = f2bf(v.y); o.z = f2bf(v.z); o.w = f2bf(v.w);
        ((ushort4*)dst)[i] = o;
    }
}

// ---------------------------------------------------------------------------
// Kernel 1: QKV projection (bf16 MFMA) + RoPE epilogue.
// Epilogue stages the 128x128 bf16 C-tile in LDS (stride 136; V transposed),
// then writes back with full-line dwordx4 stores (fixes 64x write amp).
// Q,K -> [bh][s][d] (RoPE applied); V -> [bh][d][s].
// ---------------------------------------------------------------------------
__global__ __launch_bounds__(256)
void qkv_mfma_kernel(const unsigned short* __restrict__ x16,
                     const unsigned short* __restrict__ Wq16,
                     const unsigned short* __restrict__ Wk16,
                     const unsigned short* __restrict__ Wv16,
                     const int*   __restrict__ pos,
                     unsigned short* __restrict__ Qo,
                     unsigned short* __restrict__ Ko,
                     unsigned short* __restrict__ Vt)
{
    const int which = blockIdx.z;
    const unsigned short* __restrict__ W =
        (which == 0) ? Wq16 : (which == 1) ? Wk16 : Wv16;

    __shared__ unsigned short pool[128*136];   // 34.8 KB: As/Bs during loop, C-tile after
    unsigned short* As = pool;                 // 128*32
    unsigned short* Bs = pool + 128*32;        // 128*32

    const int tid  = threadIdx.x;
    const int wave = tid >> 6;
    const int lane = tid & 63;
    const int m0 = blockIdx.y * 128;
    const int n0 = blockIdx.x * 128;
    const int wm = (wave >> 1) * 64;
    const int wn = (wave & 1) * 64;

    const int srow   = wave*32 + (lane >> 2);
    const int schunk = (lane & 3) * 8;
    const unsigned short* ga0 = x16 + (size_t)(m0 + srow     )*DM + schunk;
    const unsigned short* ga1 = x16 + (size_t)(m0 + srow + 16)*DM + schunk;
    const unsigned short* gb0 = W   + (size_t)(n0 + srow     )*DM + schunk;
    const unsigned short* gb1 = W   + (size_t)(n0 + srow + 16)*DM + schunk;
    unsigned short* la0 = As + (wave*32     )*32;
    unsigned short* la1 = As + (wave*32 + 16)*32;
    unsigned short* lb0 = Bs + (wave*32     )*32;
    unsigned short* lb1 = Bs + (wave*32 + 16)*32;

    const int fr = lane & 15;
    const int q8 = (lane >> 4) * 8;

    f32x4 acc[4][4];
    #pragma unroll
    for (int i = 0; i < 4; ++i)
        #pragma unroll
        for (int j = 0; j < 4; ++j)
            acc[i][j] = (f32x4){0.f, 0.f, 0.f, 0.f};

    for (int k0 = 0; k0 < DM; k0 += 32) {
        __syncthreads();
        GLDS(ga0 + k0, la0);
        GLDS(ga1 + k0, la1);
        GLDS(gb0 + k0, lb0);
        GLDS(gb1 + k0, lb1);
        __syncthreads();

        bf16x8 af[4], bf[4];
        #pragma unroll
        for (int i = 0; i < 4; ++i)
            af[i] = *(const bf16x8*)&As[(wm + i*16 + fr)*32 + q8];
        #pragma unroll
        for (int j = 0; j < 4; ++j)
            bf[j] = *(const bf16x8*)&Bs[(wn + j*16 + fr)*32 + q8];
        #pragma unroll
        for (int i = 0; i < 4; ++i)
            #pragma unroll
            for (int j = 0; j < 4; ++j)
                acc[i][j] = __builtin_amdgcn_mfma_f32_16x16x32_bf16(
                                af[i], bf[j], acc[i][j], 0, 0, 0);
    }

    __syncthreads();   // all waves done with As/Bs — pool is now the C-tile

    // ---- stage C (with RoPE for Q/K) into LDS ----
    const float LOGC = 0.14391156831212790f;  // ln(10000)/64
    const int col  = lane & 15;
    const int quad = lane >> 4;
    const int h0 = n0 >> 6;
    const int bI = m0 >> 11;
    const int s0 = m0 & (NS - 1);

    if (which < 2) {
        #pragma unroll
        for (int j = 0; j < 4; ++j) {
            const int c = wn + j*16 + col;        // tile-relative column
            const int d = (n0 + c) & 63;
            const int odd = d & 1;
            const float freq = expf(-(float)(d & ~1) * LOGC);
            #pragma unroll
            for (int i = 0; i < 4; ++i) {
                const int rowb = wm + i*16 + quad*4;
                #pragma unroll
                for (int r = 0; r < 4; ++r) {
                    const int s = s0 + rowb + r;
                    float v = acc[i][j][r];
                    const float pv = __shfl_xor(v, 1);
                    float sa, ca;
                    sincosf((float)pos[s] * freq, &sa, &ca);
                    v = odd ? (pv*sa + v*ca) : (v*ca - pv*sa);
                    pool[(rowb + r)*136 + c] = f2bf(v);
                }
            }
        }
    } else {
        // V: stage TRANSPOSED [c][m] so writeback is contiguous in s
        #pragma unroll
        for (int j = 0; j < 4; ++j) {
            const int c = wn + j*16 + col;
            #pragma unroll
            for (int i = 0; i < 4; ++i) {
                const int rowb = wm + i*16 + quad*4;
                ushort4 o;
                o.x = f2bf(acc[i][j][0]); o.y = f2bf(acc[i][j][1]);
                o.z = f2bf(acc[i][j][2]); o.w = f2bf(acc[i][j][3]);
                *(ushort4*)&pool[c*136 + rowb] = o;
            }
        }
    }
    __syncthreads();

    // ---- coalesced writeback: 16B/lane, 8 consecutive lanes = one 128B line ----
    if (which < 2) {
        unsigned short* __restrict__ outQK = (which == 0) ? Qo : Ko;
        #pragma unroll
        for (int rr = 0; rr < 8; ++rr) {
            const int row = rr*16 + (tid >> 4);
            const int cch = (tid & 15) * 8;
            uint4 v = *(const uint4*)&pool[row*136 + cch];
            const int h = h0 + (cch >> 6);
            const int d = cch & 63;
            *(uint4*)&outQK[(((size_t)(bI*NH + h))*NS + (s0 + row))*DK + d] = v;
        }
    } else {
        #pragma unroll
        for (int rr = 0; rr < 8; ++rr) {
            const int c   = rr*16 + (tid >> 4);
            const int sch = (tid & 15) * 8;
            uint4 v = *(const uint4*)&pool[c*136 + sch];
            const int h = h0 + (c >> 6);
            const int d = c & 63;
            *(uint4*)&Vt[(((size_t)(bI*NH + h))*DK + d)*NS + (s0 + sch)] = v;
        }
    }
}

// ---------------------------------------------------------------------------
// Kernel 2: causal flash attention, bf16 MFMA.
// O-tile staged in LDS (overlays dead Qs region) then written with full-line
// dwordx4 stores.
// ---------------------------------------------------------------------------
__global__ __launch_bounds__(256)
void attn_mfma_kernel(const unsigned short* __restrict__ Q,
                      const unsigned short* __restrict__ K,
                      const unsigned short* __restrict__ Vt,
                      unsigned short* __restrict__ O)
{
    const int qt   = blockIdx.x;      // 0..15
    const int bh   = blockIdx.y;      // 0..63
    const int tid  = threadIdx.x;
    const int wave = tid >> 6;
    const int lane = tid & 63;
    const int q0   = qt * 128;
    const int wq0  = wave * 32;

    const int fr   = lane & 15;
    const int q8   = (lane >> 4) * 8;
    const int col  = lane & 15;
    const int quad = lane >> 4;

    const unsigned short* __restrict__ Qh = Q  + (size_t)bh * NS * DK;
    const unsigned short* __restrict__ Kh = K  + (size_t)bh * NS * DK;
    const unsigned short* __restrict__ Vh = Vt + (size_t)bh * DK * NS;

    __shared__ unsigned short pool[25600];    // 50 KB
    unsigned short* Qs = pool;                // 128*64
    unsigned short* Ks = pool + 8192;         // 64*64
    unsigned short* Vs = pool + 12288;        // 64*64
    unsigned short* Ps = pool + 16384;        // 4*32*72
    // O-tile overlays pool[0..9216) with stride 72 after the loop

    // stage this wave's own 32 Q rows (4 GLDS)
    {
        const int r  = lane >> 3;
        const int c8 = (lane & 7) * 8;
        #pragma unroll
        for (int p = 0; p < 4; ++p) {
            const int row = wq0 + p*8;
            GLDS(Qh + (size_t)(q0 + row + r)*DK + c8, Qs + row*64);
        }
    }

    float m_i[2][4], l_i[2][4];
    f32x4 oacc[2][4];
    #pragma unroll
    for (int i = 0; i < 2; ++i)
        #pragma unroll
        for (int r = 0; r < 4; ++r) { m_i[i][r] = -INFINITY; l_i[i][r] = 0.f; }
    #pragma unroll
    for (int i = 0; i < 2; ++i)
        #pragma unroll
        for (int j = 0; j < 4; ++j)
            oacc[i][j] = (f32x4){0.f, 0.f, 0.f, 0.f};

    const int ktmax = (q0 + 127) >> 6;   // 2*qt+1

    for (int kt = 0; kt <= ktmax; ++kt) {
        __syncthreads();   // prior reads of Ks/Vs done
        {
            const int r  = lane >> 3;
            const int c8 = (lane & 7) * 8;
            #pragma unroll
            for (int p = 0; p < 2; ++p) {
                const int row = wave*16 + p*8;
                GLDS(Kh + (size_t)(kt*64 + row + r)*DK + c8, Ks + row*64);
                GLDS(Vh + (size_t)(row + r)*NS + kt*64 + c8, Vs + row*64);
            }
        }
        __syncthreads();   // staging drained — Q covered on first iter

        const bool active = (kt*64) <= (q0 + wq0 + 31);
        if (active) {
            // ---- S = Q K^T (wave: 32x64) ----
            f32x4 sacc[2][4];
            #pragma unroll
            for (int i = 0; i < 2; ++i)
                #pragma unroll
                for (int j = 0; j < 4; ++j)
                    sacc[i][j] = (f32x4){0.f, 0.f, 0.f, 0.f};
            #pragma unroll
            for (int kk = 0; kk < 2; ++kk) {
                bf16x8 aq[2], bk[4];
                #pragma unroll
                for (int i = 0; i < 2; ++i)
                    aq[i] = *(const bf16x8*)&Qs[(wq0 + i*16 + fr)*64 + kk*32 + q8];
                #pragma unroll
                for (int j = 0; j < 4; ++j)
                    bk[j] = *(const bf16x8*)&Ks[(j*16 + fr)*64 + kk*32 + q8];
                #pragma unroll
                for (int i = 0; i < 2; ++i)
                    #pragma unroll
                    for (int j = 0; j < 4; ++j)
                        sacc[i][j] = __builtin_amdgcn_mfma_f32_16x16x32_bf16(
                                        aq[i], bk[j], sacc[i][j], 0, 0, 0);
            }

            // ---- scale + causal mask ----
            const bool needmask = (kt*64 + 63) > (q0 + wq0);
            #pragma unroll
            for (int i = 0; i < 2; ++i)
                #pragma unroll
                for (int j = 0; j < 4; ++j)
                    #pragma unroll
                    for (int r = 0; r < 4; ++r) {
                        float v = sacc[i][j][r] * 0.125f;
                        if (needmask) {
                            const int sg = q0 + wq0 + i*16 + quad*4 + r;
                            const int kg = kt*64 + j*16 + col;
                            if (kg > sg) v = -INFINITY;
                        }
                        sacc[i][j][r] = v;
                    }

            // ---- online softmax ----
            #pragma unroll
            for (int i = 0; i < 2; ++i)
                #pragma unroll
                for (int r = 0; r < 4; ++r) {
                    float mx = fmaxf(fmaxf(sacc[i][0][r], sacc[i][1][r]),
                                     fmaxf(sacc[i][2][r], sacc[i][3][r]));
                    mx = fmaxf(mx, __shfl_xor(mx, 1));
                    mx = fmaxf(mx, __shfl_xor(mx, 2));
                    mx = fmaxf(mx, __shfl_xor(mx, 4));
                    mx = fmaxf(mx, __shfl_xor(mx, 8));
                    const float mnew  = fmaxf(m_i[i][r], mx);
                    const float alpha = __expf(m_i[i][r] - mnew);
                    float rs = 0.f;
                    #pragma unroll
                    for (int j = 0; j < 4; ++j) {
                        const float p = __expf(sacc[i][j][r] - mnew);
                        sacc[i][j][r] = p;
                        rs += p;
                    }
                    rs += __shfl_xor(rs, 1);
                    rs += __shfl_xor(rs, 2);
                    rs += __shfl_xor(rs, 4);
                    rs += __shfl_xor(rs, 8);
                    l_i[i][r] = l_i[i][r]*alpha + rs;
                    m_i[i][r] = mnew;
                    #pragma unroll
                    for (int j = 0; j < 4; ++j) oacc[i][j][r] *= alpha;
                }

            // ---- P: C-layout -> LDS [q][k] (per-wave region) ----
            unsigned short* Pw = Ps + wave*32*72;
            #pragma unroll
            for (int i = 0; i < 2; ++i)
                #pragma unroll
                for (int j = 0; j < 4; ++j)
                    #pragma unroll
                    for (int r = 0; r < 4; ++r)
                        Pw[(i*16 + quad*4 + r)*72 + j*16 + col] = f2bf(sacc[i][j][r]);
            asm volatile("s_waitcnt lgkmcnt(0)" ::: "memory");

            // ---- O += P V ----
            #pragma unroll
            for (int kk = 0; kk < 2; ++kk) {
                bf16x8 ap[2], bv[4];
                #pragma unroll
                for (int i = 0; i < 2; ++i)
                    ap[i] = *(const bf16x8*)&Pw[(i*16 + fr)*72 + kk*32 + q8];
                #pragma unroll
                for (int j = 0; j < 4; ++j)
                    bv[j] = *(const bf16x8*)&Vs[(j*16 + fr)*64 + kk*32 + q8];
                #pragma unroll
                for (int i = 0; i < 2; ++i)
                    #pragma unroll
                    for (int j = 0; j < 4; ++j)
                        oacc[i][j] = __builtin_amdgcn_mfma_f32_16x16x32_bf16(
                                        ap[i], bv[j], oacc[i][j], 0, 0, 0);
            }
        }
    }

    // ---- epilogue: O/l into LDS (stride 72), then coalesced writeback ----
    __syncthreads();   // everything in pool is dead
    #pragma unroll
    for (int i = 0; i < 2; ++i)
        #pragma unroll
        for (int r = 0; r < 4; ++r) {
            const float inv = 1.0f / l_i[i][r];
            const int row = wq0 + i*16 + quad*4 + r;
            #pragma unroll
            for (int j = 0; j < 4; ++j)
                pool[row*72 + j*16 + col] = f2bf(oacc[i][j][r] * inv);
        }
    __syncthreads();

    const int b = bh >> 4, h = bh & 15;
    #pragma unroll
    for (int pass = 0; pass < 4; ++pass) {
        const int row = pass*32 + (tid >> 3);
        const int ch  = (tid & 7) * 8;
        uint4 v = *(const uint4*)&pool[row*72 + ch];
        *(uint4*)&O[((size_t)(b*NS + q0 + row))*DM + h*64 + ch] = v;
    }
}

// ---------------------------------------------------------------------------
// Kernel 3: output projection (bf16 MFMA), fp32 output.
// ---------------------------------------------------------------------------
__global__ __launch_bounds__(256)
void proj_mfma_kernel(const unsigned short* __restrict__ A16,
                      const unsigned short* __restrict__ W16,
                      float* __restrict__ out)
{
    __shared__ unsigned short As[128*32];
    __shared__ unsigned short Bs[128*32];

    const int tid  = threadIdx.x;
    const int wave = tid >> 6;
    const int lane = tid & 63;
    const int m0 = blockIdx.y * 128;
    const int n0 = blockIdx.x * 128;
    const int wm = (wave >> 1) * 64;
    const int wn = (wave & 1) * 64;

    const int srow   = wave*32 + (lane >> 2);
    const int schunk = (lane & 3) * 8;
    const unsigned short* ga0 = A16 + (size_t)(m0 + srow     )*DM + schunk;
    const unsigned short* ga1 = A16 + (size_t)(m0 + srow + 16)*DM + schunk;
    const unsigned short* gb0 = W16 + (size_t)(n0 + srow     )*DM + schunk;
    const unsigned short* gb1 = W16 + (size_t)(n0 + srow + 16)*DM + schunk;
    unsigned short* la0 = &As[(wave*32     )*32];
    unsigned short* la1 = &As[(wave*32 + 16)*32];
    unsigned short* lb0 = &Bs[(wave*32     )*32];
    unsigned short* lb1 = &Bs[(wave*32 + 16)*32];

    const int fr = lane & 15;
    const int q8 = (lane >> 4) * 8;

    f32x4 acc[4][4];
    #pragma unroll
    for (int i = 0; i < 4; ++i)
        #pragma unroll
        for (int j = 0; j < 4; ++j)
            acc[i][j] = (f32x4){0.f, 0.f, 0.f, 0.f};

    for (int k0 = 0; k0 < DM; k0 += 32) {
        __syncthreads();
        GLDS(ga0 + k0, la0);
        GLDS(ga1 + k0, la1);
        GLDS(gb0 + k0, lb0);
        GLDS(gb1 + k0, lb1);
        __syncthreads();

        bf16x8 af[4], bf[4];
        #pragma unroll
        for (int i = 0; i < 4; ++i)
            af[i] = *(const bf16x8*)&As[(wm + i*16 + fr)*32 + q8];
        #pragma unroll
        for (int j = 0; j < 4; ++j)
            bf[j] = *(const bf16x8*)&Bs[(wn + j*16 + fr)*32 + q8];
        #pragma unroll
        for (int i = 0; i < 4; ++i)
            #pragma unroll
            for (int j = 0; j < 4; ++j)
                acc[i][j] = __builtin_amdgcn_mfma_f32_16x16x32_bf16(
                                af[i], bf[j], acc[i][j], 0, 0, 0);
    }

    const int col  = lane & 15;
    const int quad = lane >> 4;
    #pragma unroll
    for (int j = 0; j < 4; ++j) {
        const int n = n0 + wn + j*16 + col;
        #pragma unroll
        for (int i = 0; i < 4; ++i) {
            #pragma unroll
            for (int r = 0; r < 4; ++r) {
                const int m = m0 + wm + i*16 + quad*4 + r;
                out[(size_t)m*DM + n] = acc[i][j][r];
            }
        }
    }
}

// ---------------------------------------------------------------------------
extern "C" void kernel_launch(void* const* d_in, const int* in_sizes, int n_in,
                              void* d_out, int out_size, void* d_ws, size_t ws_size,
                              hipStream_t stream)
{
    const float* x   = (const float*)d_in[0];
    const float* Wq  = (const float*)d_in[1];
    const float* Wk  = (const float*)d_in[2];
    const float* Wv  = (const float*)d_in[3];
    const float* Wo  = (const float*)d_in[4];
    const int*   pos = (const int*)d_in[5];
    float* out = (float*)d_out;

    const size_t per = (size_t)NB*NH*NS*DK;   // 8388608 elements
    unsigned short* x16  = (unsigned short*)d_ws;
    unsigned short* Wq16 = x16  + per;
    unsigned short* Wk16 = Wq16 + (size_t)DM*DM;
    unsigned short* Wv16 = Wk16 + (size_t)DM*DM;
    unsigned short* Wo16 = Wv16 + (size_t)DM*DM;
    unsigned short* Q16  = Wo16 + (size_t)DM*DM;
    unsigned short* K16  = Q16  + per;
    unsigned short* Vt16 = K16  + per;
    unsigned short* Ab16 = Vt16 + per;        // attention out, bf16 [B][S][DM]

    dim3 blk(256);
    cvt_kernel<<<dim3((int)(per/4/256)), blk, 0, stream>>>(x, x16, (int)(per/4));
    cvt_kernel<<<dim3(DM*DM/4/256), blk, 0, stream>>>(Wq, Wq16, DM*DM/4);
    cvt_kernel<<<dim3(DM*DM/4/256), blk, 0, stream>>>(Wk, Wk16, DM*DM/4);
    cvt_kernel<<<dim3(DM*DM/4/256), blk, 0, stream>>>(Wv, Wv16, DM*DM/4);
    cvt_kernel<<<dim3(DM*DM/4/256), blk, 0, stream>>>(Wo, Wo16, DM*DM/4);

    qkv_mfma_kernel<<<dim3(DM/128, NM/128, 3), blk, 0, stream>>>(
        x16, Wq16, Wk16, Wv16, pos, Q16, K16, Vt16);
    attn_mfma_kernel<<<dim3(NS/128, NB*NH), blk, 0, stream>>>(Q16, K16, Vt16, Ab16);
    proj_mfma_kernel<<<dim3(DM/128, NM/128), blk, 0, stream>>>(Ab16, Wo16, out);
}

// Round 6
// 496.887 us; speedup vs baseline: 5.1710x; 1.8881x over previous
//
#include <hip/hip_runtime.h>
#include <math.h>

#define DM 1024
#define NH 16
#define DK 64
#define NB 4
#define NS 2048
#define NM (NB*NS)   // 8192 rows

typedef __attribute__((ext_vector_type(8))) __bf16 bf16x8;
typedef __attribute__((ext_vector_type(4))) float  f32x4;

// async global->LDS, 16B per lane, dest = wave-uniform base + lane*16
#define GLDS(gp, lp) __builtin_amdgcn_global_load_lds( \
    (const __attribute__((address_space(1))) void*)(gp), \
    (__attribute__((address_space(3))) void*)(lp), 16, 0, 0)

__device__ __forceinline__ unsigned short f2bf(float f) {
    unsigned int u = __float_as_uint(f);
    unsigned int r = (u + 0x7FFFu + ((u >> 16) & 1u)) >> 16;   // RNE
    return (unsigned short)r;
}

// ---------------------------------------------------------------------------
// fp32 -> bf16 convert
// ---------------------------------------------------------------------------
__global__ __launch_bounds__(256)
void cvt_kernel(const float* __restrict__ src, unsigned short* __restrict__ dst, int n4)
{
    int i = blockIdx.x * 256 + threadIdx.x;
    if (i < n4) {
        float4 v = ((const float4*)src)[i];
        ushort4 o;
        o.x = f2bf(v.x); o.y = f2bf(v.y); o.z = f2bf(v.z); o.w = f2bf(v.w);
        ((ushort4*)dst)[i] = o;
    }
}

// ---------------------------------------------------------------------------
// RoPE cos/sin table: tab[s][k] = {cos, sin}(pos[s] * theta^(-2k/64)),
// s in [0,NS), k in [0,32). 512 KB, L2/L3-resident. One sincosf per thread
// (scratch slow-path traffic here is ~3 MB total, vs ~GBs when inlined
// 64x/thread in the GEMM epilogue).
// ---------------------------------------------------------------------------
__global__ __launch_bounds__(256)
void rope_tab_kernel(const int* __restrict__ pos, float* __restrict__ tab)
{
    const float LOGC = 0.14391156831212790f;  // ln(10000)/64
    int i = blockIdx.x * 256 + threadIdx.x;   // [0, NS*32)
    int s = i >> 5, k = i & 31;
    float freq = expf(-(float)(2*k) * LOGC);
    float sa, ca;
    sincosf((float)pos[s] * freq, &sa, &ca);
    tab[2*i]     = ca;
    tab[2*i + 1] = sa;
}

// ---------------------------------------------------------------------------
// Kernel 1: QKV projection (bf16 MFMA) + RoPE epilogue (table-driven).
// GLDS staging (R4-proven). C-tile staged in LDS; coalesced writeback.
// Q,K -> [bh][s][d] (RoPE applied); V -> [bh][d][s].
// ---------------------------------------------------------------------------
__global__ __launch_bounds__(256)
void qkv_mfma_kernel(const unsigned short* __restrict__ x16,
                     const unsigned short* __restrict__ Wq16,
                     const unsigned short* __restrict__ Wk16,
                     const unsigned short* __restrict__ Wv16,
                     const float* __restrict__ ropeTab,
                     unsigned short* __restrict__ Qo,
                     unsigned short* __restrict__ Ko,
                     unsigned short* __restrict__ Vt)
{
    const int which = blockIdx.z;
    const unsigned short* __restrict__ W =
        (which == 0) ? Wq16 : (which == 1) ? Wk16 : Wv16;

    __shared__ unsigned short pool[128*136];   // As/Bs during loop, C-tile after
    unsigned short* As = pool;                 // 128*32
    unsigned short* Bs = pool + 128*32;        // 128*32

    const int tid  = threadIdx.x;
    const int wave = tid >> 6;
    const int lane = tid & 63;
    const int m0 = blockIdx.y * 128;
    const int n0 = blockIdx.x * 128;
    const int wm = (wave >> 1) * 64;
    const int wn = (wave & 1) * 64;

    const int srow   = wave*32 + (lane >> 2);
    const int schunk = (lane & 3) * 8;
    const unsigned short* ga0 = x16 + (size_t)(m0 + srow     )*DM + schunk;
    const unsigned short* ga1 = x16 + (size_t)(m0 + srow + 16)*DM + schunk;
    const unsigned short* gb0 = W   + (size_t)(n0 + srow     )*DM + schunk;
    const unsigned short* gb1 = W   + (size_t)(n0 + srow + 16)*DM + schunk;
    unsigned short* la0 = As + (wave*32     )*32;
    unsigned short* la1 = As + (wave*32 + 16)*32;
    unsigned short* lb0 = Bs + (wave*32     )*32;
    unsigned short* lb1 = Bs + (wave*32 + 16)*32;

    const int fr = lane & 15;
    const int q8 = (lane >> 4) * 8;

    f32x4 acc[4][4];
    #pragma unroll
    for (int i = 0; i < 4; ++i)
        #pragma unroll
        for (int j = 0; j < 4; ++j)
            acc[i][j] = (f32x4){0.f, 0.f, 0.f, 0.f};

    for (int k0 = 0; k0 < DM; k0 += 32) {
        __syncthreads();
        GLDS(ga0 + k0, la0);
        GLDS(ga1 + k0, la1);
        GLDS(gb0 + k0, lb0);
        GLDS(gb1 + k0, lb1);
        __syncthreads();

        bf16x8 af[4], bf[4];
        #pragma unroll
        for (int i = 0; i < 4; ++i)
            af[i] = *(const bf16x8*)&As[(wm + i*16 + fr)*32 + q8];
        #pragma unroll
        for (int j = 0; j < 4; ++j)
            bf[j] = *(const bf16x8*)&Bs[(wn + j*16 + fr)*32 + q8];
        #pragma unroll
        for (int i = 0; i < 4; ++i)
            #pragma unroll
            for (int j = 0; j < 4; ++j)
                acc[i][j] = __builtin_amdgcn_mfma_f32_16x16x32_bf16(
                                af[i], bf[j], acc[i][j], 0, 0, 0);
    }

    __syncthreads();   // all waves done with As/Bs — pool is now the C-tile

    // ---- stage C (with RoPE for Q/K) into LDS ----
    const int col  = lane & 15;
    const int quad = lane >> 4;
    const int h0 = n0 >> 6;
    const int bI = m0 >> 11;
    const int s0 = m0 & (NS - 1);

    if (which < 2) {
        #pragma unroll
        for (int j = 0; j < 4; ++j) {
            const int c = wn + j*16 + col;        // tile-relative column
            const int d = (n0 + c) & 63;
            const int odd = d & 1;
            const int kidx = d >> 1;              // pair index in [0,32)
            #pragma unroll
            for (int i = 0; i < 4; ++i) {
                const int rowb = wm + i*16 + quad*4;
                #pragma unroll
                for (int r = 0; r < 4; ++r) {
                    const int s = s0 + rowb + r;
                    float v = acc[i][j][r];
                    const float pv = __shfl_xor(v, 1);
                    const float2 cs = *(const float2*)&ropeTab[(s*32 + kidx)*2];
                    v = odd ? (pv*cs.y + v*cs.x) : (v*cs.x - pv*cs.y);
                    pool[(rowb + r)*136 + c] = f2bf(v);
                }
            }
        }
    } else {
        // V: stage TRANSPOSED [c][m] so writeback is contiguous in s
        #pragma unroll
        for (int j = 0; j < 4; ++j) {
            const int c = wn + j*16 + col;
            #pragma unroll
            for (int i = 0; i < 4; ++i) {
                const int rowb = wm + i*16 + quad*4;
                ushort4 o;
                o.x = f2bf(acc[i][j][0]); o.y = f2bf(acc[i][j][1]);
                o.z = f2bf(acc[i][j][2]); o.w = f2bf(acc[i][j][3]);
                *(ushort4*)&pool[c*136 + rowb] = o;
            }
        }
    }
    __syncthreads();

    // ---- coalesced writeback: 16B/lane, 8 consecutive lanes = one 128B line ----
    if (which < 2) {
        unsigned short* __restrict__ outQK = (which == 0) ? Qo : Ko;
        #pragma unroll
        for (int rr = 0; rr < 8; ++rr) {
            const int row = rr*16 + (tid >> 4);
            const int cch = (tid & 15) * 8;
            uint4 v = *(const uint4*)&pool[row*136 + cch];
            const int h = h0 + (cch >> 6);
            const int d = cch & 63;
            *(uint4*)&outQK[(((size_t)(bI*NH + h))*NS + (s0 + row))*DK + d] = v;
        }
    } else {
        #pragma unroll
        for (int rr = 0; rr < 8; ++rr) {
            const int c   = rr*16 + (tid >> 4);
            const int sch = (tid & 15) * 8;
            uint4 v = *(const uint4*)&pool[c*136 + sch];
            const int h = h0 + (c >> 6);
            const int d = c & 63;
            *(uint4*)&Vt[(((size_t)(bI*NH + h))*DK + d)*NS + (s0 + sch)] = v;
        }
    }
}

// ---------------------------------------------------------------------------
// Kernel 2: causal flash attention, bf16 MFMA (R4-proven GLDS version).
// ---------------------------------------------------------------------------
__global__ __launch_bounds__(256)
void attn_mfma_kernel(const unsigned short* __restrict__ Q,
                      const unsigned short* __restrict__ K,
                      const unsigned short* __restrict__ Vt,
                      unsigned short* __restrict__ O)
{
    const int qt   = blockIdx.x;      // 0..15
    const int bh   = blockIdx.y;      // 0..63
    const int tid  = threadIdx.x;
    const int wave = tid >> 6;
    const int lane = tid & 63;
    const int q0   = qt * 128;
    const int wq0  = wave * 32;

    const int fr   = lane & 15;
    const int q8   = (lane >> 4) * 8;
    const int col  = lane & 15;
    const int quad = lane >> 4;

    const unsigned short* __restrict__ Qh = Q  + (size_t)bh * NS * DK;
    const unsigned short* __restrict__ Kh = K  + (size_t)bh * NS * DK;
    const unsigned short* __restrict__ Vh = Vt + (size_t)bh * DK * NS;

    __shared__ unsigned short pool[25600];    // 50 KB
    unsigned short* Qs = pool;                // 128*64
    unsigned short* Ks = pool + 8192;         // 64*64
    unsigned short* Vs = pool + 12288;        // 64*64
    unsigned short* Ps = pool + 16384;        // 4*32*72
    // O-tile overlays pool[0..9216) with stride 72 after the loop

    // stage this wave's own 32 Q rows (4 GLDS)
    {
        const int r  = lane >> 3;
        const int c8 = (lane & 7) * 8;
        #pragma unroll
        for (int p = 0; p < 4; ++p) {
            const int row = wq0 + p*8;
            GLDS(Qh + (size_t)(q0 + row + r)*DK + c8, Qs + row*64);
        }
    }

    float m_i[2][4], l_i[2][4];
    f32x4 oacc[2][4];
    #pragma unroll
    for (int i = 0; i < 2; ++i)
        #pragma unroll
        for (int r = 0; r < 4; ++r) { m_i[i][r] = -INFINITY; l_i[i][r] = 0.f; }
    #pragma unroll
    for (int i = 0; i < 2; ++i)
        #pragma unroll
        for (int j = 0; j < 4; ++j)
            oacc[i][j] = (f32x4){0.f, 0.f, 0.f, 0.f};

    const int ktmax = (q0 + 127) >> 6;   // 2*qt+1

    for (int kt = 0; kt <= ktmax; ++kt) {
        __syncthreads();   // prior reads of Ks/Vs done
        {
            const int r  = lane >> 3;
            const int c8 = (lane & 7) * 8;
            #pragma unroll
            for (int p = 0; p < 2; ++p) {
                const int row = wave*16 + p*8;
                GLDS(Kh + (size_t)(kt*64 + row + r)*DK + c8, Ks + row*64);
                GLDS(Vh + (size_t)(row + r)*NS + kt*64 + c8, Vs + row*64);
            }
        }
        __syncthreads();   // staging drained — Q covered on first iter

        const bool active = (kt*64) <= (q0 + wq0 + 31);
        if (active) {
            // ---- S = Q K^T (wave: 32x64) ----
            f32x4 sacc[2][4];
            #pragma unroll
            for (int i = 0; i < 2; ++i)
                #pragma unroll
                for (int j = 0; j < 4; ++j)
                    sacc[i][j] = (f32x4){0.f, 0.f, 0.f, 0.f};
            #pragma unroll
            for (int kk = 0; kk < 2; ++kk) {
                bf16x8 aq[2], bk[4];
                #pragma unroll
                for (int i = 0; i < 2; ++i)
                    aq[i] = *(const bf16x8*)&Qs[(wq0 + i*16 + fr)*64 + kk*32 + q8];
                #pragma unroll
                for (int j = 0; j < 4; ++j)
                    bk[j] = *(const bf16x8*)&Ks[(j*16 + fr)*64 + kk*32 + q8];
                #pragma unroll
                for (int i = 0; i < 2; ++i)
                    #pragma unroll
                    for (int j = 0; j < 4; ++j)
                        sacc[i][j] = __builtin_amdgcn_mfma_f32_16x16x32_bf16(
                                        aq[i], bk[j], sacc[i][j], 0, 0, 0);
            }

            // ---- scale + causal mask ----
            const bool needmask = (kt*64 + 63) > (q0 + wq0);
            #pragma unroll
            for (int i = 0; i < 2; ++i)
                #pragma unroll
                for (int j = 0; j < 4; ++j)
                    #pragma unroll
                    for (int r = 0; r < 4; ++r) {
                        float v = sacc[i][j][r] * 0.125f;
                        if (needmask) {
                            const int sg = q0 + wq0 + i*16 + quad*4 + r;
                            const int kg = kt*64 + j*16 + col;
                            if (kg > sg) v = -INFINITY;
                        }
                        sacc[i][j][r] = v;
                    }

            // ---- online softmax ----
            #pragma unroll
            for (int i = 0; i < 2; ++i)
                #pragma unroll
                for (int r = 0; r < 4; ++r) {
                    float mx = fmaxf(fmaxf(sacc[i][0][r], sacc[i][1][r]),
                                     fmaxf(sacc[i][2][r], sacc[i][3][r]));
                    mx = fmaxf(mx, __shfl_xor(mx, 1));
                    mx = fmaxf(mx, __shfl_xor(mx, 2));
                    mx = fmaxf(mx, __shfl_xor(mx, 4));
                    mx = fmaxf(mx, __shfl_xor(mx, 8));
                    const float mnew  = fmaxf(m_i[i][r], mx);
                    const float alpha = __expf(m_i[i][r] - mnew);
                    float rs = 0.f;
                    #pragma unroll
                    for (int j = 0; j < 4; ++j) {
                        const float p = __expf(sacc[i][j][r] - mnew);
                        sacc[i][j][r] = p;
                        rs += p;
                    }
                    rs += __shfl_xor(rs, 1);
                    rs += __shfl_xor(rs, 2);
                    rs += __shfl_xor(rs, 4);
                    rs += __shfl_xor(rs, 8);
                    l_i[i][r] = l_i[i][r]*alpha + rs;
                    m_i[i][r] = mnew;
                    #pragma unroll
                    for (int j = 0; j < 4; ++j) oacc[i][j][r] *= alpha;
                }

            // ---- P: C-layout -> LDS [q][k] (per-wave region) ----
            unsigned short* Pw = Ps + wave*32*72;
            #pragma unroll
            for (int i = 0; i < 2; ++i)
                #pragma unroll
                for (int j = 0; j < 4; ++j)
                    #pragma unroll
                    for (int r = 0; r < 4; ++r)
                        Pw[(i*16 + quad*4 + r)*72 + j*16 + col] = f2bf(sacc[i][j][r]);
            asm volatile("s_waitcnt lgkmcnt(0)" ::: "memory");

            // ---- O += P V ----
            #pragma unroll
            for (int kk = 0; kk < 2; ++kk) {
                bf16x8 ap[2], bv[4];
                #pragma unroll
                for (int i = 0; i < 2; ++i)
                    ap[i] = *(const bf16x8*)&Pw[(i*16 + fr)*72 + kk*32 + q8];
                #pragma unroll
                for (int j = 0; j < 4; ++j)
                    bv[j] = *(const bf16x8*)&Vs[(j*16 + fr)*64 + kk*32 + q8];
                #pragma unroll
                for (int i = 0; i < 2; ++i)
                    #pragma unroll
                    for (int j = 0; j < 4; ++j)
                        oacc[i][j] = __builtin_amdgcn_mfma_f32_16x16x32_bf16(
                                        ap[i], bv[j], oacc[i][j], 0, 0, 0);
            }
        }
    }

    // ---- epilogue: O/l into LDS (stride 72), then coalesced writeback ----
    __syncthreads();   // everything in pool is dead
    #pragma unroll
    for (int i = 0; i < 2; ++i)
        #pragma unroll
        for (int r = 0; r < 4; ++r) {
            const float inv = 1.0f / l_i[i][r];
            const int row = wq0 + i*16 + quad*4 + r;
            #pragma unroll
            for (int j = 0; j < 4; ++j)
                pool[row*72 + j*16 + col] = f2bf(oacc[i][j][r] * inv);
        }
    __syncthreads();

    const int b = bh >> 4, h = bh & 15;
    #pragma unroll
    for (int pass = 0; pass < 4; ++pass) {
        const int row = pass*32 + (tid >> 3);
        const int ch  = (tid & 7) * 8;
        uint4 v = *(const uint4*)&pool[row*72 + ch];
        *(uint4*)&O[((size_t)(b*NS + q0 + row))*DM + h*64 + ch] = v;
    }
}

// ---------------------------------------------------------------------------
// Kernel 3: output projection (bf16 MFMA), fp32 output (R4-proven).
// ---------------------------------------------------------------------------
__global__ __launch_bounds__(256)
void proj_mfma_kernel(const unsigned short* __restrict__ A16,
                      const unsigned short* __restrict__ W16,
                      float* __restrict__ out)
{
    __shared__ unsigned short As[128*32];
    __shared__ unsigned short Bs[128*32];

    const int tid  = threadIdx.x;
    const int wave = tid >> 6;
    const int lane = tid & 63;
    const int m0 = blockIdx.y * 128;
    const int n0 = blockIdx.x * 128;
    const int wm = (wave >> 1) * 64;
    const int wn = (wave & 1) * 64;

    const int srow   = wave*32 + (lane >> 2);
    const int schunk = (lane & 3) * 8;
    const unsigned short* ga0 = A16 + (size_t)(m0 + srow     )*DM + schunk;
    const unsigned short* ga1 = A16 + (size_t)(m0 + srow + 16)*DM + schunk;
    const unsigned short* gb0 = W16 + (size_t)(n0 + srow     )*DM + schunk;
    const unsigned short* gb1 = W16 + (size_t)(n0 + srow + 16)*DM + schunk;
    unsigned short* la0 = &As[(wave*32     )*32];
    unsigned short* la1 = &As[(wave*32 + 16)*32];
    unsigned short* lb0 = &Bs[(wave*32     )*32];
    unsigned short* lb1 = &Bs[(wave*32 + 16)*32];

    const int fr = lane & 15;
    const int q8 = (lane >> 4) * 8;

    f32x4 acc[4][4];
    #pragma unroll
    for (int i = 0; i < 4; ++i)
        #pragma unroll
        for (int j = 0; j < 4; ++j)
            acc[i][j] = (f32x4){0.f, 0.f, 0.f, 0.f};

    for (int k0 = 0; k0 < DM; k0 += 32) {
        __syncthreads();
        GLDS(ga0 + k0, la0);
        GLDS(ga1 + k0, la1);
        GLDS(gb0 + k0, lb0);
        GLDS(gb1 + k0, lb1);
        __syncthreads();

        bf16x8 af[4], bf[4];
        #pragma unroll
        for (int i = 0; i < 4; ++i)
            af[i] = *(const bf16x8*)&As[(wm + i*16 + fr)*32 + q8];
        #pragma unroll
        for (int j = 0; j < 4; ++j)
            bf[j] = *(const bf16x8*)&Bs[(wn + j*16 + fr)*32 + q8];
        #pragma unroll
        for (int i = 0; i < 4; ++i)
            #pragma unroll
            for (int j = 0; j < 4; ++j)
                acc[i][j] = __builtin_amdgcn_mfma_f32_16x16x32_bf16(
                                af[i], bf[j], acc[i][j], 0, 0, 0);
    }

    const int col  = lane & 15;
    const int quad = lane >> 4;
    #pragma unroll
    for (int j = 0; j < 4; ++j) {
        const int n = n0 + wn + j*16 + col;
        #pragma unroll
        for (int i = 0; i < 4; ++i) {
            #pragma unroll
            for (int r = 0; r < 4; ++r) {
                const int m = m0 + wm + i*16 + quad*4 + r;
                out[(size_t)m*DM + n] = acc[i][j][r];
            }
        }
    }
}

// ---------------------------------------------------------------------------
extern "C" void kernel_launch(void* const* d_in, const int* in_sizes, int n_in,
                              void* d_out, int out_size, void* d_ws, size_t ws_size,
                              hipStream_t stream)
{
    const float* x   = (const float*)d_in[0];
    const float* Wq  = (const float*)d_in[1];
    const float* Wk  = (const float*)d_in[2];
    const float* Wv  = (const float*)d_in[3];
    const float* Wo  = (const float*)d_in[4];
    const int*   pos = (const int*)d_in[5];
    float* out = (float*)d_out;

    const size_t per = (size_t)NB*NH*NS*DK;   // 8388608 elements
    unsigned short* x16  = (unsigned short*)d_ws;
    unsigned short* Wq16 = x16  + per;
    unsigned short* Wk16 = Wq16 + (size_t)DM*DM;
    unsigned short* Wv16 = Wk16 + (size_t)DM*DM;
    unsigned short* Wo16 = Wv16 + (size_t)DM*DM;
    unsigned short* Q16  = Wo16 + (size_t)DM*DM;
    unsigned short* K16  = Q16  + per;
    unsigned short* Vt16 = K16  + per;
    unsigned short* Ab16 = Vt16 + per;        // attention out, bf16 [B][S][DM]
    float* ropeTab = (float*)(Ab16 + per);    // [NS][32][2] fp32, 512 KB

    dim3 blk(256);
    cvt_kernel<<<dim3((int)(per/4/256)), blk, 0, stream>>>(x, x16, (int)(per/4));
    cvt_kernel<<<dim3(DM*DM/4/256), blk, 0, stream>>>(Wq, Wq16, DM*DM/4);
    cvt_kernel<<<dim3(DM*DM/4/256), blk, 0, stream>>>(Wk, Wk16, DM*DM/4);
    cvt_kernel<<<dim3(DM*DM/4/256), blk, 0, stream>>>(Wv, Wv16, DM*DM/4);
    cvt_kernel<<<dim3(DM*DM/4/256), blk, 0, stream>>>(Wo, Wo16, DM*DM/4);
    rope_tab_kernel<<<dim3(NS*32/256), blk, 0, stream>>>(pos, ropeTab);

    qkv_mfma_kernel<<<dim3(DM/128, NM/128, 3), blk, 0, stream>>>(
        x16, Wq16, Wk16, Wv16, ropeTab, Q16, K16, Vt16);
    attn_mfma_kernel<<<dim3(NS/128, NB*NH), blk, 0, stream>>>(Q16, K16, Vt16, Ab16);
    proj_mfma_kernel<<<dim3(DM/128, NM/128), blk, 0, stream>>>(Ab16, Wo16, out);
}

// Round 7
// 426.478 us; speedup vs baseline: 6.0247x; 1.1651x over previous
//
#include <hip/hip_runtime.h>
#include <math.h>

#define DM 1024
#define NH 16
#define DK 64
#define NB 4
#define NS 2048
#define NM (NB*NS)   // 8192 rows

typedef __attribute__((ext_vector_type(8))) __bf16 bf16x8;
typedef __attribute__((ext_vector_type(4))) float  f32x4;

// async global->LDS, 16B per lane, LDS dest = wave-uniform base + lane*16.
// Global address is per-lane (normal VGPR addressing) — we exploit this to
// land XOR-swizzled layouts in LDS.
#define GLDS(gp, lp) __builtin_amdgcn_global_load_lds( \
    (const __attribute__((address_space(1))) void*)(gp), \
    (__attribute__((address_space(3))) void*)(lp), 16, 0, 0)

__device__ __forceinline__ unsigned short f2bf(float f) {
    unsigned int u = __float_as_uint(f);
    unsigned int r = (u + 0x7FFFu + ((u >> 16) & 1u)) >> 16;   // RNE
    return (unsigned short)r;
}

// ---------------------------------------------------------------------------
// Fused prep: fp32->bf16 for x and the 4 weights, plus the RoPE cos/sin table
// (sincosf ONLY here — in-epilogue sincosf causes GBs of scratch HBM writes,
// measured R3-R6). tab[s][k] = {cos,sin}(pos[s] * theta^(-2k/64)).
// ---------------------------------------------------------------------------
__global__ __launch_bounds__(256)
void prep_kernel(const float* __restrict__ x,
                 const float* __restrict__ Wq, const float* __restrict__ Wk,
                 const float* __restrict__ Wv, const float* __restrict__ Wo,
                 const int*   __restrict__ pos,
                 unsigned short* __restrict__ x16,
                 unsigned short* __restrict__ Wq16, unsigned short* __restrict__ Wk16,
                 unsigned short* __restrict__ Wv16, unsigned short* __restrict__ Wo16,
                 float* __restrict__ tab)
{
    const int NX4 = (NB*NS*DM)/4;      // 2097152
    const int NW4 = (DM*DM)/4;         // 262144
    int i = blockIdx.x * 256 + threadIdx.x;
    if (i < NX4) {
        float4 v = ((const float4*)x)[i];
        ushort4 o;
        o.x = f2bf(v.x); o.y = f2bf(v.y); o.z = f2bf(v.z); o.w = f2bf(v.w);
        ((ushort4*)x16)[i] = o;
    } else if (i < NX4 + 4*NW4) {
        int j = i - NX4;
        int w = j >> 18;               // NW4 = 2^18
        int k = j & (NW4 - 1);
        const float* s = (w==0) ? Wq : (w==1) ? Wk : (w==2) ? Wv : Wo;
        unsigned short* d = (w==0) ? Wq16 : (w==1) ? Wk16 : (w==2) ? Wv16 : Wo16;
        float4 v = ((const float4*)s)[k];
        ushort4 o;
        o.x = f2bf(v.x); o.y = f2bf(v.y); o.z = f2bf(v.z); o.w = f2bf(v.w);
        ((ushort4*)d)[k] = o;
    } else {
        int j = i - NX4 - 4*NW4;       // [0, NS*32)
        if (j < NS*32) {
            const float LOGC = 0.14391156831212790f;  // ln(10000)/64
            int s = j >> 5, k = j & 31;
            float freq = expf(-(float)(2*k) * LOGC);
            float sa, ca;
            sincosf((float)pos[s] * freq, &sa, &ca);
            tab[2*j]     = ca;
            tab[2*j + 1] = sa;
        }
    }
}

// ---------------------------------------------------------------------------
// Kernel 1: QKV projection (bf16 MFMA) + table-RoPE epilogue.
// Double-buffered GLDS staging (separate LDS objects, one barrier per slab).
// Per-wave epilogue staging (64x64) -> full-line writeback.
// Q,K -> [bh][s][d]; V -> [bh][d][s].
// ---------------------------------------------------------------------------
__global__ __launch_bounds__(256)
void qkv_mfma_kernel(const unsigned short* __restrict__ x16,
                     const unsigned short* __restrict__ Wq16,
                     const unsigned short* __restrict__ Wk16,
                     const unsigned short* __restrict__ Wv16,
                     const float* __restrict__ ropeTab,
                     unsigned short* __restrict__ Qo,
                     unsigned short* __restrict__ Ko,
                     unsigned short* __restrict__ Vt)
{
    const int which = blockIdx.z;
    const unsigned short* __restrict__ W =
        (which == 0) ? Wq16 : (which == 1) ? Wk16 : Wv16;

    __shared__ unsigned short As0[4096], As1[4096], Bs0[4096], Bs1[4096];

    const int tid  = threadIdx.x;
    const int wave = tid >> 6;
    const int lane = tid & 63;
    const int m0 = blockIdx.y * 128;
    const int n0 = blockIdx.x * 128;
    const int wm = (wave >> 1) * 64;
    const int wn = (wave & 1) * 64;

    const int srow   = wave*32 + (lane >> 2);
    const int schunk = (lane & 3) * 8;
    const unsigned short* ga0 = x16 + (size_t)(m0 + srow     )*DM + schunk;
    const unsigned short* ga1 = x16 + (size_t)(m0 + srow + 16)*DM + schunk;
    const unsigned short* gb0 = W   + (size_t)(n0 + srow     )*DM + schunk;
    const unsigned short* gb1 = W   + (size_t)(n0 + srow + 16)*DM + schunk;
    const int lofs = wave*1024;        // this wave's staging region (32 rows * 32)

    const int fr = lane & 15;
    const int q8 = (lane >> 4) * 8;

    f32x4 acc[4][4];
    #pragma unroll
    for (int i = 0; i < 4; ++i)
        #pragma unroll
        for (int j = 0; j < 4; ++j)
            acc[i][j] = (f32x4){0.f, 0.f, 0.f, 0.f};

    auto gemm_step = [&](const unsigned short* A, const unsigned short* B) {
        bf16x8 af[4], bfr[4];
        #pragma unroll
        for (int i = 0; i < 4; ++i)
            af[i] = *(const bf16x8*)&A[(wm + i*16 + fr)*32 + q8];
        #pragma unroll
        for (int j = 0; j < 4; ++j)
            bfr[j] = *(const bf16x8*)&B[(wn + j*16 + fr)*32 + q8];
        #pragma unroll
        for (int i = 0; i < 4; ++i)
            #pragma unroll
            for (int j = 0; j < 4; ++j)
                acc[i][j] = __builtin_amdgcn_mfma_f32_16x16x32_bf16(
                                af[i], bfr[j], acc[i][j], 0, 0, 0);
    };

    // prologue: stage slab 0 into buf0
    GLDS(ga0, As0 + lofs);  GLDS(ga1, As0 + lofs + 512);
    GLDS(gb0, Bs0 + lofs);  GLDS(gb1, Bs0 + lofs + 512);

    for (int k0 = 0; k0 < DM; k0 += 64) {
        __syncthreads();                            // slab k0 landed (vmcnt drain)
        GLDS(ga0 + k0 + 32, As1 + lofs);  GLDS(ga1 + k0 + 32, As1 + lofs + 512);
        GLDS(gb0 + k0 + 32, Bs1 + lofs);  GLDS(gb1 + k0 + 32, Bs1 + lofs + 512);
        gemm_step(As0, Bs0);
        __syncthreads();                            // slab k0+32 landed
        if (k0 + 64 < DM) {
            GLDS(ga0 + k0 + 64, As0 + lofs);  GLDS(ga1 + k0 + 64, As0 + lofs + 512);
            GLDS(gb0 + k0 + 64, Bs0 + lofs);  GLDS(gb1 + k0 + 64, Bs0 + lofs + 512);
        }
        gemm_step(As1, Bs1);
    }
    __syncthreads();    // all waves done reading staging buffers

    // ---- per-wave epilogue: stage 64x64 piece, then full-line writeback ----
    unsigned short* ws = (wave==0) ? As0 : (wave==1) ? As1 : (wave==2) ? Bs0 : Bs1;
    const int col  = lane & 15;
    const int quad = lane >> 4;
    const int hW = (n0 + wn) >> 6;     // one head per wave half-tile
    const int bI = m0 >> 11;
    const int s0 = m0 & (NS - 1);

    if (which < 2) {
        #pragma unroll
        for (int j = 0; j < 4; ++j) {
            const int cl = j*16 + col;         // = d (head-local), n0+wn mult of 64
            const int odd  = cl & 1;
            const int kidx = cl >> 1;
            #pragma unroll
            for (int i = 0; i < 4; ++i) {
                const int rowb = i*16 + quad*4;
                #pragma unroll
                for (int r = 0; r < 4; ++r) {
                    const int s = s0 + wm + rowb + r;
                    float v = acc[i][j][r];
                    const float pv = __shfl_xor(v, 1);
                    const float2 cs = *(const float2*)&ropeTab[(s*32 + kidx)*2];
                    v = odd ? (pv*cs.y + v*cs.x) : (v*cs.x - pv*cs.y);
                    ws[(rowb + r)*64 + cl] = f2bf(v);
                }
            }
        }
    } else {
        // V: stage transposed [d][m]
        #pragma unroll
        for (int j = 0; j < 4; ++j) {
            const int cl = j*16 + col;
            #pragma unroll
            for (int i = 0; i < 4; ++i) {
                const int rowb = i*16 + quad*4;
                ushort4 o;
                o.x = f2bf(acc[i][j][0]); o.y = f2bf(acc[i][j][1]);
                o.z = f2bf(acc[i][j][2]); o.w = f2bf(acc[i][j][3]);
                *(ushort4*)&ws[cl*64 + rowb] = o;
            }
        }
    }
    asm volatile("s_waitcnt lgkmcnt(0)" ::: "memory");

    if (which < 2) {
        unsigned short* __restrict__ outQK = (which == 0) ? Qo : Ko;
        #pragma unroll
        for (int pass = 0; pass < 8; ++pass) {
            const int rowl = pass*8 + (lane >> 3);
            const int ch   = (lane & 7) * 8;
            uint4 v = *(const uint4*)&ws[rowl*64 + ch];
            *(uint4*)&outQK[((size_t)(bI*NH + hW)*NS + (s0 + wm + rowl))*DK + ch] = v;
        }
    } else {
        #pragma unroll
        for (int pass = 0; pass < 8; ++pass) {
            const int rowl = pass*8 + (lane >> 3);   // = d
            const int ch   = (lane & 7) * 8;         // m-chunk
            uint4 v = *(const uint4*)&ws[rowl*64 + ch];
            *(uint4*)&Vt[((size_t)(bI*NH + hW)*DK + rowl)*NS + (s0 + wm + ch)] = v;
        }
    }
}

// ---------------------------------------------------------------------------
// Kernel 2: causal flash attention, bf16 MFMA.
// - K/V double-buffered in separate LDS objects, ONE barrier per 64-key tile
//   (prefetch kt+1 after the barrier, compute kt; barrier's vmcnt drain covers
//   the in-flight prefetch that has had a full tile of compute to land).
// - XOR-swizzled Q/K/V LDS layout (phys chunk = logical ^ (row&7)) via GLDS
//   per-lane global addressing -> bank-uniform ds_read_b128.
// - qt remapped heavy-first to cut the causal tail.
// - per-wave O epilogue (no extra barriers).
// ---------------------------------------------------------------------------
__global__ __launch_bounds__(256)
void attn_mfma_kernel(const unsigned short* __restrict__ Q,
                      const unsigned short* __restrict__ K,
                      const unsigned short* __restrict__ Vt,
                      unsigned short* __restrict__ O)
{
    const int qt   = (NS/128 - 1) - blockIdx.x;   // heavy blocks first
    const int bh   = blockIdx.y;                  // 0..63
    const int tid  = threadIdx.x;
    const int wave = tid >> 6;
    const int lane = tid & 63;
    const int q0   = qt * 128;
    const int wq0  = wave * 32;

    const int fr   = lane & 15;
    const int col  = lane & 15;
    const int quad = lane >> 4;
    const int swz  = lane & 7;        // == fr & 7

    const unsigned short* __restrict__ Qh = Q  + (size_t)bh * NS * DK;
    const unsigned short* __restrict__ Kh = K  + (size_t)bh * NS * DK;
    const unsigned short* __restrict__ Vh = Vt + (size_t)bh * DK * NS;

    __shared__ unsigned short Qs[8192];              // 128 x 64, swizzled
    __shared__ unsigned short Ks0[4096], Ks1[4096];  // 64 x 64, swizzled
    __shared__ unsigned short Vs0[4096], Vs1[4096];  // 64 x 64 (V^T), swizzled
    __shared__ unsigned short Ps[9216];              // 4 waves x 32 x 72

    // ---- staging (swizzled source chunk = (lane&7) ^ row-in-group) ----
    {
        const int r  = lane >> 3;
        const int gq = (lane & 7) ^ r;
        #pragma unroll
        for (int p = 0; p < 4; ++p) {
            const int row = wq0 + p*8;
            GLDS(Qh + (size_t)(q0 + row + r)*DK + gq*8, Qs + row*64);
        }
    }
    auto stageKV = [&](int kt, unsigned short* Ksb, unsigned short* Vsb) {
        const int r  = lane >> 3;
        const int gq = (lane & 7) ^ r;
        #pragma unroll
        for (int p2 = 0; p2 < 2; ++p2) {
            const int row = wave*16 + p2*8;
            GLDS(Kh + (size_t)(kt*64 + row + r)*DK + gq*8, Ksb + row*64);
            GLDS(Vh + (size_t)(row + r)*NS + kt*64 + gq*8, Vsb + row*64);
        }
    };

    float m_i[2][4], l_i[2][4];
    f32x4 oacc[2][4];
    #pragma unroll
    for (int i = 0; i < 2; ++i)
        #pragma unroll
        for (int r = 0; r < 4; ++r) { m_i[i][r] = -INFINITY; l_i[i][r] = 0.f; }
    #pragma unroll
    for (int i = 0; i < 2; ++i)
        #pragma unroll
        for (int j = 0; j < 4; ++j)
            oacc[i][j] = (f32x4){0.f, 0.f, 0.f, 0.f};

    auto tile = [&](int kt, const unsigned short* Ksb, const unsigned short* Vsb) {
        if ((kt*64) > (q0 + wq0 + 31)) return;   // fully masked for this wave

        // ---- S = Q K^T (wave: 32x64) ----
        f32x4 sacc[2][4];
        #pragma unroll
        for (int i = 0; i < 2; ++i)
            #pragma unroll
            for (int j = 0; j < 4; ++j)
                sacc[i][j] = (f32x4){0.f, 0.f, 0.f, 0.f};
        #pragma unroll
        for (int kk = 0; kk < 2; ++kk) {
            const int po = ((kk*4 + quad) ^ swz) * 8;   // swizzled chunk offset
            bf16x8 aq[2], bk[4];
            #pragma unroll
            for (int i = 0; i < 2; ++i)
                aq[i] = *(const bf16x8*)&Qs[(wq0 + i*16 + fr)*64 + po];
            #pragma unroll
            for (int j = 0; j < 4; ++j)
                bk[j] = *(const bf16x8*)&Ksb[(j*16 + fr)*64 + po];
            #pragma unroll
            for (int i = 0; i < 2; ++i)
                #pragma unroll
                for (int j = 0; j < 4; ++j)
                    sacc[i][j] = __builtin_amdgcn_mfma_f32_16x16x32_bf16(
                                    aq[i], bk[j], sacc[i][j], 0, 0, 0);
        }

        // ---- scale + causal mask ----
        const bool needmask = (kt*64 + 63) > (q0 + wq0);
        #pragma unroll
        for (int i = 0; i < 2; ++i)
            #pragma unroll
            for (int j = 0; j < 4; ++j)
                #pragma unroll
                for (int r = 0; r < 4; ++r) {
                    float v = sacc[i][j][r] * 0.125f;
                    if (needmask) {
                        const int sg = q0 + wq0 + i*16 + quad*4 + r;
                        const int kg = kt*64 + j*16 + col;
                        if (kg > sg) v = -INFINITY;
                    }
                    sacc[i][j][r] = v;
                }

        // ---- online softmax ----
        #pragma unroll
        for (int i = 0; i < 2; ++i)
            #pragma unroll
            for (int r = 0; r < 4; ++r) {
                float mx = fmaxf(fmaxf(sacc[i][0][r], sacc[i][1][r]),
                                 fmaxf(sacc[i][2][r], sacc[i][3][r]));
                mx = fmaxf(mx, __shfl_xor(mx, 1));
                mx = fmaxf(mx, __shfl_xor(mx, 2));
                mx = fmaxf(mx, __shfl_xor(mx, 4));
                mx = fmaxf(mx, __shfl_xor(mx, 8));
                const float mnew  = fmaxf(m_i[i][r], mx);
                const float alpha = __expf(m_i[i][r] - mnew);
                float rs = 0.f;
                #pragma unroll
                for (int j = 0; j < 4; ++j) {
                    const float p = __expf(sacc[i][j][r] - mnew);
                    sacc[i][j][r] = p;
                    rs += p;
                }
                rs += __shfl_xor(rs, 1);
                rs += __shfl_xor(rs, 2);
                rs += __shfl_xor(rs, 4);
                rs += __shfl_xor(rs, 8);
                l_i[i][r] = l_i[i][r]*alpha + rs;
                m_i[i][r] = mnew;
                #pragma unroll
                for (int j = 0; j < 4; ++j) oacc[i][j][r] *= alpha;
            }

        // ---- P: C-layout -> per-wave LDS [q][k], stride 72 ----
        unsigned short* Pw = Ps + wave*2304;
        #pragma unroll
        for (int i = 0; i < 2; ++i)
            #pragma unroll
            for (int j = 0; j < 4; ++j)
                #pragma unroll
                for (int r = 0; r < 4; ++r)
                    Pw[(i*16 + quad*4 + r)*72 + j*16 + col] = f2bf(sacc[i][j][r]);
        asm volatile("s_waitcnt lgkmcnt(0)" ::: "memory");

        // ---- O += P V ----
        #pragma unroll
        for (int kk = 0; kk < 2; ++kk) {
            const int po = ((kk*4 + quad) ^ swz) * 8;
            const int pq = kk*32 + quad*8;            // P is NOT swizzled
            bf16x8 ap[2], bv[4];
            #pragma unroll
            for (int i = 0; i < 2; ++i)
                ap[i] = *(const bf16x8*)&Pw[(i*16 + fr)*72 + pq];
            #pragma unroll
            for (int j = 0; j < 4; ++j)
                bv[j] = *(const bf16x8*)&Vsb[(j*16 + fr)*64 + po];
            #pragma unroll
            for (int i = 0; i < 2; ++i)
                #pragma unroll
                for (int j = 0; j < 4; ++j)
                    oacc[i][j] = __builtin_amdgcn_mfma_f32_16x16x32_bf16(
                                    ap[i], bv[j], oacc[i][j], 0, 0, 0);
        }
    };

    const int ktmax = 2*qt + 1;        // odd -> tiles come in exact pairs
    stageKV(0, Ks0, Vs0);
    for (int kt = 0; kt <= ktmax; kt += 2) {
        __syncthreads();                               // tile kt landed
        stageKV(kt+1, Ks1, Vs1);                       // prefetch (kt+1 <= ktmax)
        tile(kt, Ks0, Vs0);
        __syncthreads();                               // tile kt+1 landed
        if (kt + 2 <= ktmax) stageKV(kt+2, Ks0, Vs0);
        tile(kt+1, Ks1, Vs1);
    }

    // ---- per-wave epilogue: O/l -> Ps region (stride 64), line writeback ----
    unsigned short* Ow = Ps + wave*2304;
    #pragma unroll
    for (int i = 0; i < 2; ++i)
        #pragma unroll
        for (int r = 0; r < 4; ++r) {
            const float inv = 1.0f / l_i[i][r];
            const int rowl = i*16 + quad*4 + r;
            #pragma unroll
            for (int j = 0; j < 4; ++j)
                Ow[rowl*64 + j*16 + col] = f2bf(oacc[i][j][r] * inv);
        }
    asm volatile("s_waitcnt lgkmcnt(0)" ::: "memory");

    const int b = bh >> 4, h = bh & 15;
    #pragma unroll
    for (int pass = 0; pass < 4; ++pass) {
        const int rowl = pass*8 + (lane >> 3);
        const int ch   = (lane & 7) * 8;
        uint4 v = *(const uint4*)&Ow[rowl*64 + ch];
        *(uint4*)&O[((size_t)(b*NS + q0 + wq0 + rowl))*DM + h*64 + ch] = v;
    }
}

// ---------------------------------------------------------------------------
// Kernel 3: output projection (bf16 MFMA), dbuf staging, fp32 output.
// ---------------------------------------------------------------------------
__global__ __launch_bounds__(256)
void proj_mfma_kernel(const unsigned short* __restrict__ A16,
                      const unsigned short* __restrict__ W16,
                      float* __restrict__ out)
{
    __shared__ unsigned short As0[4096], As1[4096], Bs0[4096], Bs1[4096];

    const int tid  = threadIdx.x;
    const int wave = tid >> 6;
    const int lane = tid & 63;
    const int m0 = blockIdx.y * 128;
    const int n0 = blockIdx.x * 128;
    const int wm = (wave >> 1) * 64;
    const int wn = (wave & 1) * 64;

    const int srow   = wave*32 + (lane >> 2);
    const int schunk = (lane & 3) * 8;
    const unsigned short* ga0 = A16 + (size_t)(m0 + srow     )*DM + schunk;
    const unsigned short* ga1 = A16 + (size_t)(m0 + srow + 16)*DM + schunk;
    const unsigned short* gb0 = W16 + (size_t)(n0 + srow     )*DM + schunk;
    const unsigned short* gb1 = W16 + (size_t)(n0 + srow + 16)*DM + schunk;
    const int lofs = wave*1024;

    const int fr = lane & 15;
    const int q8 = (lane >> 4) * 8;

    f32x4 acc[4][4];
    #pragma unroll
    for (int i = 0; i < 4; ++i)
        #pragma unroll
        for (int j = 0; j < 4; ++j)
            acc[i][j] = (f32x4){0.f, 0.f, 0.f, 0.f};

    auto gemm_step = [&](const unsigned short* A, const unsigned short* B) {
        bf16x8 af[4], bfr[4];
        #pragma unroll
        for (int i = 0; i < 4; ++i)
            af[i] = *(const bf16x8*)&A[(wm + i*16 + fr)*32 + q8];
        #pragma unroll
        for (int j = 0; j < 4; ++j)
            bfr[j] = *(const bf16x8*)&B[(wn + j*16 + fr)*32 + q8];
        #pragma unroll
        for (int i = 0; i < 4; ++i)
            #pragma unroll
            for (int j = 0; j < 4; ++j)
                acc[i][j] = __builtin_amdgcn_mfma_f32_16x16x32_bf16(
                                af[i], bfr[j], acc[i][j], 0, 0, 0);
    };

    GLDS(ga0, As0 + lofs);  GLDS(ga1, As0 + lofs + 512);
    GLDS(gb0, Bs0 + lofs);  GLDS(gb1, Bs0 + lofs + 512);

    for (int k0 = 0; k0 < DM; k0 += 64) {
        __syncthreads();
        GLDS(ga0 + k0 + 32, As1 + lofs);  GLDS(ga1 + k0 + 32, As1 + lofs + 512);
        GLDS(gb0 + k0 + 32, Bs1 + lofs);  GLDS(gb1 + k0 + 32, Bs1 + lofs + 512);
        gemm_step(As0, Bs0);
        __syncthreads();
        if (k0 + 64 < DM) {
            GLDS(ga0 + k0 + 64, As0 + lofs);  GLDS(ga1 + k0 + 64, As0 + lofs + 512);
            GLDS(gb0 + k0 + 64, Bs0 + lofs);  GLDS(gb1 + k0 + 64, Bs0 + lofs + 512);
        }
        gemm_step(As1, Bs1);
    }

    const int col  = lane & 15;
    const int quad = lane >> 4;
    #pragma unroll
    for (int j = 0; j < 4; ++j) {
        const int n = n0 + wn + j*16 + col;
        #pragma unroll
        for (int i = 0; i < 4; ++i) {
            #pragma unroll
            for (int r = 0; r < 4; ++r) {
                const int m = m0 + wm + i*16 + quad*4 + r;
                out[(size_t)m*DM + n] = acc[i][j][r];
            }
        }
    }
}

// ---------------------------------------------------------------------------
extern "C" void kernel_launch(void* const* d_in, const int* in_sizes, int n_in,
                              void* d_out, int out_size, void* d_ws, size_t ws_size,
                              hipStream_t stream)
{
    const float* x   = (const float*)d_in[0];
    const float* Wq  = (const float*)d_in[1];
    const float* Wk  = (const float*)d_in[2];
    const float* Wv  = (const float*)d_in[3];
    const float* Wo  = (const float*)d_in[4];
    const int*   pos = (const int*)d_in[5];
    float* out = (float*)d_out;

    const size_t per = (size_t)NB*NH*NS*DK;   // 8388608 elements
    unsigned short* x16  = (unsigned short*)d_ws;
    unsigned short* Wq16 = x16  + per;
    unsigned short* Wk16 = Wq16 + (size_t)DM*DM;
    unsigned short* Wv16 = Wk16 + (size_t)DM*DM;
    unsigned short* Wo16 = Wv16 + (size_t)DM*DM;
    unsigned short* Q16  = Wo16 + (size_t)DM*DM;
    unsigned short* K16  = Q16  + per;
    unsigned short* Vt16 = K16  + per;
    unsigned short* Ab16 = Vt16 + per;        // attention out, bf16 [B][S][DM]
    float* ropeTab = (float*)(Ab16 + per);    // [NS][32][2] fp32

    dim3 blk(256);
    const int prep_blocks = ((NB*NS*DM)/4 + 4*(DM*DM)/4 + NS*32) / 256;  // 12544
    prep_kernel<<<dim3(prep_blocks), blk, 0, stream>>>(
        x, Wq, Wk, Wv, Wo, pos, x16, Wq16, Wk16, Wv16, Wo16, ropeTab);

    qkv_mfma_kernel<<<dim3(DM/128, NM/128, 3), blk, 0, stream>>>(
        x16, Wq16, Wk16, Wv16, ropeTab, Q16, K16, Vt16);
    attn_mfma_kernel<<<dim3(NS/128, NB*NH), blk, 0, stream>>>(Q16, K16, Vt16, Ab16);
    proj_mfma_kernel<<<dim3(DM/128, NM/128), blk, 0, stream>>>(Ab16, Wo16, out);
}